// Round 7
// baseline (164.741 us; speedup 1.0000x reference)
//
#include <hip/hip_runtime.h>
#include <hip/hip_bf16.h>

#define N_LIG 100000
#define N_TGT 4000
#define NEDGE 150000
#define DT 1280
#define HD 128
#define CAP_L 32
#define CAP_T 128
#define NTILE_L 6250            // N_LIG / 16
#define NTILE_PAD 6252

typedef __attribute__((ext_vector_type(8))) short short8v;
typedef __attribute__((ext_vector_type(4))) float f32x4;

static __device__ __forceinline__ ushort f2bf(float f) {
    __hip_bfloat16 h = __float2bfloat16(f);
    union { __hip_bfloat16 h; ushort u; } c; c.h = h; return c.u;
}
static __device__ __forceinline__ float bf2f(ushort u) {
    union { unsigned v; float f; } c; c.v = ((unsigned)u) << 16; return c.f;
}

// ---------------------------------------------------------------------------
// K0: merged prep — weight/x_t fragment packing + counter zeroing.
//   blocks [0,8):      Wf  = W2tl_r as B-frags (2048 threads)
//   blocks [8,168):    Wf1 = {W1lt_r|W1tl_l} as B-frags (40960 threads)
//   blocks [168,2668): xtf = x_t as bf16 A-frags (640000 threads)
//   blocks [2668,2770): zero cnt_src/cnt_dst (26000 int4)
// ---------------------------------------------------------------------------
__global__ __launch_bounds__(256) void k_pack(
    const float* __restrict__ W2, uint4* __restrict__ Wf,
    const float* __restrict__ Wr, const float* __restrict__ Wl,
    uint4* __restrict__ Wf1,
    const float* __restrict__ xt, uint4* __restrict__ xtf,
    int4* __restrict__ cntz)
{
    int bx = blockIdx.x;
    if (bx < 8) {
        int gid = bx * 256 + threadIdx.x;           // 2048
        int lane = gid & 63, frag = gid >> 6;       // frag 0..31
        int ks = frag >> 3, ct = frag & 7;
        int l15 = lane & 15, g = lane >> 4;
        int k = ks * 32 + g * 4, n = ct * 16 + l15;
        union { ushort us[8]; uint4 u; } o;
#pragma unroll
        for (int j = 0; j < 4; ++j) {
            o.us[j]     = f2bf(W2[(size_t)(k + j) * HD + n]);
            o.us[4 + j] = f2bf(W2[(size_t)(k + 16 + j) * HD + n]);
        }
        Wf[gid] = o.u;
    } else if (bx < 168) {
        int gid = (bx - 8) * 256 + threadIdx.x;     // 40960
        int lane = gid & 63, frag = gid >> 6;       // 0..639
        int ks = frag >> 4, nct = frag & 15;
        int l15 = lane & 15, g = lane >> 4;
        int k = ks * 32 + g * 4, n = nct * 16 + l15;
        const float* Ws = (n < HD) ? Wr : Wl;
        int nn = n & 127;
        union { ushort us[8]; uint4 u; } o;
#pragma unroll
        for (int j = 0; j < 4; ++j) {
            o.us[j]     = f2bf(Ws[(size_t)(k + j) * HD + nn]);
            o.us[4 + j] = f2bf(Ws[(size_t)(k + 16 + j) * HD + nn]);
        }
        Wf1[gid] = o.u;
    } else if (bx < 2668) {
        int gid = (bx - 168) * 256 + threadIdx.x;   // 640000
        int lane = gid & 63, frag = gid >> 6;       // 0..9999
        int ks = frag % 40, rt = frag / 40;
        int row = rt * 16 + (lane & 15);
        int kb = ks * 32 + (lane >> 4) * 4;
        float4 a0 = *reinterpret_cast<const float4*>(xt + (size_t)row * DT + kb);
        float4 a1 = *reinterpret_cast<const float4*>(xt + (size_t)row * DT + kb + 16);
        union { ushort us[8]; uint4 u; } o;
        o.us[0] = f2bf(a0.x); o.us[1] = f2bf(a0.y); o.us[2] = f2bf(a0.z); o.us[3] = f2bf(a0.w);
        o.us[4] = f2bf(a1.x); o.us[5] = f2bf(a1.y); o.us[6] = f2bf(a1.z); o.us[7] = f2bf(a1.w);
        xtf[gid] = o.u;
    } else {
        int i = (bx - 2668) * 256 + threadIdx.x;
        if (i < 26000) cntz[i] = make_int4(0, 0, 0, 0);
    }
}

// ---------------------------------------------------------------------------
// K1: build adjacency buckets (int atomics only).
// ---------------------------------------------------------------------------
__global__ __launch_bounds__(256) void k_fill(
    const int* __restrict__ src, const int* __restrict__ dst,
    int* __restrict__ cnt_src, int* __restrict__ cnt_dst,
    int* __restrict__ bsrc, int* __restrict__ bdst)
{
    int e = blockIdx.x * 256 + threadIdx.x;
    if (e >= NEDGE) return;
    int s = src[e], d = dst[e];
    int ps = atomicAdd(&cnt_src[s], 1);
    if (ps < CAP_L) bsrc[(size_t)s * CAP_L + ps] = d;
    int pd = atomicAdd(&cnt_dst[d], 1);
    if (pd < CAP_T) bdst[(size_t)d * CAP_T + pd] = s;
}

// ---------------------------------------------------------------------------
// K1d: m_t[t][0..3] = mean_{src in bucket} x_l[src]
// ---------------------------------------------------------------------------
__global__ __launch_bounds__(256) void k_mt(
    const float* __restrict__ xl,
    const int* __restrict__ bdst, const int* __restrict__ cnt_dst,
    float* __restrict__ m_t)
{
    int t = blockIdx.x * 256 + threadIdx.x;
    int row = t >> 3, lane8 = t & 7;
    if (row >= N_TGT) return;
    int deg = cnt_dst[row];
    int n = min(deg, CAP_T);
    float4 acc = make_float4(0.f, 0.f, 0.f, 0.f);
    for (int i = lane8; i < n; i += 8) {
        int sid = bdst[(size_t)row * CAP_T + i];
        float4 x = *reinterpret_cast<const float4*>(xl + 4ull * (unsigned)sid);
        acc.x += x.x; acc.y += x.y; acc.z += x.z; acc.w += x.w;
    }
#pragma unroll
    for (int off = 1; off < 8; off <<= 1) {
        acc.x += __shfl_xor(acc.x, off); acc.y += __shfl_xor(acc.y, off);
        acc.z += __shfl_xor(acc.z, off); acc.w += __shfl_xor(acc.w, off);
    }
    if (lane8 == 0) {
        float dinv = 1.0f / fmaxf((float)deg, 1.0f);
        float4 o = make_float4(acc.x * dinv, acc.y * dinv, acc.z * dinv, acc.w * dinv);
        *reinterpret_cast<float4*>(m_t + 4 * row) = o;
    }
}

// ---------------------------------------------------------------------------
// K2: MFMA target conv1 — all operand loads 16B coalesced from packed frags.
// ---------------------------------------------------------------------------
__global__ __launch_bounds__(256) void k_tgt1m(
    const uint4* __restrict__ xtf,    // [250*40][64] bf16 A-frags
    const uint4* __restrict__ Wf1,    // [640][64] bf16 B-frags
    const float* __restrict__ m_t,    // [4000,4]
    const float* __restrict__ W1lt_l, // [4,128]
    const float* __restrict__ b1lt,
    float* __restrict__ h_t, float* __restrict__ y_t1)
{
    int w = threadIdx.x >> 6;
    int lane = threadIdx.x & 63;
    int l15 = lane & 15, g = lane >> 4;
    int rt = blockIdx.x;
    int row0 = rt * 16;
    int cb = w * 64;

    f32x4 acc[4];
#pragma unroll
    for (int ct = 0; ct < 4; ++ct) acc[ct] = (f32x4){0.f, 0.f, 0.f, 0.f};

    for (int ks = 0; ks < DT / 32; ++ks) {
        union { uint4 u; short8v s; } ua;
        ua.u = xtf[(size_t)(rt * 40 + ks) * 64 + lane];
#pragma unroll
        for (int ct = 0; ct < 4; ++ct) {
            int nct = w * 4 + ct;
            union { uint4 u; short8v s; } ub;
            ub.u = Wf1[(size_t)(ks * 16 + nct) * 64 + lane];
            acc[ct] = __builtin_amdgcn_mfma_f32_16x16x32_bf16(ua.s, ub.s, acc[ct], 0, 0, 0);
        }
    }

    if (w < 2) {
#pragma unroll
        for (int ct = 0; ct < 4; ++ct) {
            int c = cb + ct * 16 + l15;
            float wl0 = W1lt_l[c], wl1 = W1lt_l[HD + c],
                  wl2 = W1lt_l[2 * HD + c], wl3 = W1lt_l[3 * HD + c];
            float bb = b1lt[c];
#pragma unroll
            for (int j = 0; j < 4; ++j) {
                int grow = row0 + 4 * g + j;
                float4 m = *reinterpret_cast<const float4*>(m_t + 4 * grow);
                float v = acc[ct][j] + bb + m.x * wl0 + m.y * wl1 + m.z * wl2 + m.w * wl3;
                h_t[(size_t)grow * HD + c] = fmaxf(v, 0.0f);
            }
        }
    } else {
#pragma unroll
        for (int ct = 0; ct < 4; ++ct) {
            int c = cb - HD + ct * 16 + l15;
#pragma unroll
            for (int j = 0; j < 4; ++j) {
                int grow = row0 + 4 * g + j;
                y_t1[(size_t)grow * HD + c] = acc[ct][j];
            }
        }
    }
}

// ---------------------------------------------------------------------------
// K3: fused ligand conv1 -> hlbf (fragment layout ONLY).
// Block = 16 nodes; 16 threads/node; thread tc=(ks,g) owns cols
// ks*32+g*4+{0..3} and +16..+19 (one full A-fragment uint4).
// ---------------------------------------------------------------------------
__global__ __launch_bounds__(256) void k_hl(
    const float* __restrict__ xl, const float* __restrict__ y_t1,
    const int* __restrict__ bsrc, const int* __restrict__ cnt_src,
    const float* __restrict__ W1tl_r,  // [4,128]
    const float* __restrict__ b1tl,
    uint4* __restrict__ hlbf)
{
    int tc = threadIdx.x & 15;
    int node = blockIdx.x * 16 + (threadIdx.x >> 4);
    int ks = tc >> 2, g = tc & 3;
    int kb = ks * 32 + g * 4;

    int deg = cnt_src[node];
    int n = min(deg, CAP_L);
    float4 s0 = make_float4(0.f, 0.f, 0.f, 0.f);
    float4 s1 = make_float4(0.f, 0.f, 0.f, 0.f);
    for (int i = 0; i < n; ++i) {
        int did = bsrc[(size_t)node * CAP_L + i];
        float4 v0 = *reinterpret_cast<const float4*>(y_t1 + (size_t)did * HD + kb);
        float4 v1 = *reinterpret_cast<const float4*>(y_t1 + (size_t)did * HD + kb + 16);
        s0.x += v0.x; s0.y += v0.y; s0.z += v0.z; s0.w += v0.w;
        s1.x += v1.x; s1.y += v1.y; s1.z += v1.z; s1.w += v1.w;
    }
    float dinv = 1.0f / fmaxf((float)deg, 1.0f);
    float4 x = *reinterpret_cast<const float4*>(xl + 4ull * (unsigned)node);

    float4 b0 = *reinterpret_cast<const float4*>(b1tl + kb);
    float4 b1 = *reinterpret_cast<const float4*>(b1tl + kb + 16);
    float4 wa0 = *reinterpret_cast<const float4*>(W1tl_r + 0 * HD + kb);
    float4 wa1 = *reinterpret_cast<const float4*>(W1tl_r + 1 * HD + kb);
    float4 wa2 = *reinterpret_cast<const float4*>(W1tl_r + 2 * HD + kb);
    float4 wa3 = *reinterpret_cast<const float4*>(W1tl_r + 3 * HD + kb);
    float4 wb0 = *reinterpret_cast<const float4*>(W1tl_r + 0 * HD + kb + 16);
    float4 wb1 = *reinterpret_cast<const float4*>(W1tl_r + 1 * HD + kb + 16);
    float4 wb2 = *reinterpret_cast<const float4*>(W1tl_r + 2 * HD + kb + 16);
    float4 wb3 = *reinterpret_cast<const float4*>(W1tl_r + 3 * HD + kb + 16);

    union { ushort us[8]; uint4 u; } o;
    o.us[0] = f2bf(fmaxf(s0.x * dinv + b0.x + x.x * wa0.x + x.y * wa1.x + x.z * wa2.x + x.w * wa3.x, 0.f));
    o.us[1] = f2bf(fmaxf(s0.y * dinv + b0.y + x.x * wa0.y + x.y * wa1.y + x.z * wa2.y + x.w * wa3.y, 0.f));
    o.us[2] = f2bf(fmaxf(s0.z * dinv + b0.z + x.x * wa0.z + x.y * wa1.z + x.z * wa2.z + x.w * wa3.z, 0.f));
    o.us[3] = f2bf(fmaxf(s0.w * dinv + b0.w + x.x * wa0.w + x.y * wa1.w + x.z * wa2.w + x.w * wa3.w, 0.f));
    o.us[4] = f2bf(fmaxf(s1.x * dinv + b1.x + x.x * wb0.x + x.y * wb1.x + x.z * wb2.x + x.w * wb3.x, 0.f));
    o.us[5] = f2bf(fmaxf(s1.y * dinv + b1.y + x.x * wb0.y + x.y * wb1.y + x.z * wb2.y + x.w * wb3.y, 0.f));
    o.us[6] = f2bf(fmaxf(s1.z * dinv + b1.z + x.x * wb0.z + x.y * wb1.z + x.z * wb2.z + x.w * wb3.z, 0.f));
    o.us[7] = f2bf(fmaxf(s1.w * dinv + b1.w + x.x * wb0.w + x.y * wb1.w + x.z * wb2.w + x.w * wb3.w, 0.f));

    int lane = (node & 15) + 16 * g;
    hlbf[(size_t)(blockIdx.x * 4 + ks) * 64 + lane] = o.u;
}

// ---------------------------------------------------------------------------
// K4: h_t [4000,128] @ {W2tl_l, W2lt_r} -> y_t2, htW2r
// ---------------------------------------------------------------------------
__global__ __launch_bounds__(256) void k_tgt_gemm2(
    const float* __restrict__ ht,
    const float* __restrict__ Wl,   // W2tl_l [128,128]
    const float* __restrict__ Wr,   // W2lt_r [128,128]
    float* __restrict__ y_t2,
    float* __restrict__ htW2r)
{
    __shared__ float xs[8][HD];
    int row0 = blockIdx.x * 8;
    const float4* srcv = reinterpret_cast<const float4*>(ht + (size_t)row0 * HD);
    float4* dstv = reinterpret_cast<float4*>(&xs[0][0]);
    for (int i = threadIdx.x; i < 8 * HD / 4; i += 256) dstv[i] = srcv[i];
    __syncthreads();

    int n = threadIdx.x;
    const float* W = (n < HD) ? (Wl + n) : (Wr + (n - HD));
    float acc[8] = {0.f,0.f,0.f,0.f,0.f,0.f,0.f,0.f};
    for (int k = 0; k < HD; k += 4) {
        float w0 = W[(size_t)(k + 0) * HD];
        float w1 = W[(size_t)(k + 1) * HD];
        float w2 = W[(size_t)(k + 2) * HD];
        float w3 = W[(size_t)(k + 3) * HD];
#pragma unroll
        for (int r = 0; r < 8; ++r) {
            float4 a = *reinterpret_cast<const float4*>(&xs[r][k]);
            acc[r] += a.x * w0 + a.y * w1 + a.z * w2 + a.w * w3;
        }
    }
    float* o = (n < HD) ? (y_t2 + (size_t)row0 * HD + n)
                        : (htW2r + (size_t)row0 * HD + (n - HD));
#pragma unroll
    for (int r = 0; r < 8; ++r) o[(size_t)r * HD] = acc[r];
}

// ---------------------------------------------------------------------------
// K5: fused target conv2 + predictor; neighbor rows gathered from the
// FRAGMENT layout (16 threads/chunk-set, 16 neighbor groups), LDS reduce,
// then the 128-thread GEMM column phase.
// ---------------------------------------------------------------------------
__global__ __launch_bounds__(256) void k_pt(
    const uint4* __restrict__ hlbf,
    const int* __restrict__ bdst, const int* __restrict__ cnt_dst,
    const float* __restrict__ W,    // W2lt_l [128,128]
    const float* __restrict__ b,    // b2lt
    const float* __restrict__ htW2r,
    const float* __restrict__ Wp,   // [256]
    float* __restrict__ p_t)
{
    __shared__ float sm[16][132];   // [wg][tc*8+j], padded stride
    __shared__ float msh[HD];
    __shared__ float sum2[2];
    int row = blockIdx.x;
    int wg = threadIdx.x >> 4;      // neighbor group 0..15
    int tc = threadIdx.x & 15;      // (ks,g) chunk id
    int ks = tc >> 2, g = tc & 3;
    int deg = cnt_dst[row];
    int nn = min(deg, CAP_T);

    float s[8];
#pragma unroll
    for (int j = 0; j < 8; ++j) s[j] = 0.f;
    for (int i = wg; i < nn; i += 16) {
        int sid = bdst[(size_t)row * CAP_T + i];
        union { uint4 u; ushort us[8]; } v;
        v.u = hlbf[(size_t)((sid >> 4) * 4 + ks) * 64 + (sid & 15) + 16 * g];
#pragma unroll
        for (int j = 0; j < 8; ++j) s[j] += bf2f(v.us[j]);
    }
#pragma unroll
    for (int j = 0; j < 8; ++j) sm[wg][tc * 8 + j] = s[j];
    __syncthreads();

    if (threadIdx.x < HD) {
        int tc2 = threadIdx.x >> 3, jj = threadIdx.x & 7;
        int idx = tc2 * 8 + jj;
        float acc = 0.f;
#pragma unroll
        for (int w2 = 0; w2 < 16; ++w2) acc += sm[w2][idx];
        int ks2 = tc2 >> 2, g2 = tc2 & 3;
        int col = ks2 * 32 + ((jj >> 2) << 4) + g2 * 4 + (jj & 3);
        msh[col] = acc / fmaxf((float)deg, 1.0f);
    }
    __syncthreads();

    if (threadIdx.x < HD) {
        int h = threadIdx.x;
        float g2 = 0.f;
        for (int k = 0; k < HD; k += 4) {
            float4 mk = *reinterpret_cast<const float4*>(&msh[k]);
            g2 += mk.x * W[(size_t)(k + 0) * HD + h] + mk.y * W[(size_t)(k + 1) * HD + h]
                + mk.z * W[(size_t)(k + 2) * HD + h] + mk.w * W[(size_t)(k + 3) * HD + h];
        }
        float v = fmaxf(g2 + b[h] + htW2r[(size_t)row * HD + h], 0.0f);
        float part = v * Wp[HD + h];
#pragma unroll
        for (int off = 1; off < 64; off <<= 1) part += __shfl_xor(part, off);
        if ((h & 63) == 0) sum2[h >> 6] = part;
    }
    __syncthreads();
    if (threadIdx.x == 0) p_t[row] = sum2[0] + sum2[1];
}

// ---------------------------------------------------------------------------
// K6: ligand conv2 + predictor via MFMA; fused y_t2 neighbor-mean epilogue.
// ---------------------------------------------------------------------------
__global__ __launch_bounds__(256) void k_pl(
    const uint4* __restrict__ hlbf,   // [NTILE_PAD*4][64] A-frags
    const uint4* __restrict__ Wf,     // [32][64] B-frags
    const float* __restrict__ y_t2,
    const int* __restrict__ bsrc, const int* __restrict__ cnt_src,
    const float* __restrict__ b,      // b2tl
    const float* __restrict__ Wp,     // [256]; ligand part = Wp[0..127]
    float* __restrict__ p_l)
{
    int wid = threadIdx.x >> 6;
    int lane = threadIdx.x & 63;
    int l15 = lane & 15, g = lane >> 4;
    int tile = blockIdx.x * 4 + wid;
    int wrow0 = tile * 16;

    f32x4 acc[8];
#pragma unroll
    for (int ct = 0; ct < 8; ++ct) acc[ct] = (f32x4){0.f, 0.f, 0.f, 0.f};

#pragma unroll
    for (int ks = 0; ks < 4; ++ks) {
        union { uint4 u; short8v s; } ua;
        ua.u = hlbf[(size_t)(tile * 4 + ks) * 64 + lane];
#pragma unroll
        for (int ct = 0; ct < 8; ++ct) {
            union { uint4 u; short8v s; } ub;
            ub.u = Wf[(ks * 8 + ct) * 64 + lane];
            acc[ct] = __builtin_amdgcn_mfma_f32_16x16x32_bf16(ua.s, ub.s, acc[ct], 0, 0, 0);
        }
    }

    float wpv[8], bv[8];
#pragma unroll
    for (int ct = 0; ct < 8; ++ct) {
        int c = ct * 16 + l15;
        wpv[ct] = Wp[c];
        bv[ct]  = b[c];
    }

#pragma unroll
    for (int j = 0; j < 4; ++j) {
        int row = wrow0 + g * 4 + j;
        bool valid = row < N_LIG;
        int deg = valid ? cnt_src[row] : 0;
        int nn = min(deg, CAP_L);
        float dinv = 1.0f / fmaxf((float)deg, 1.0f);
        float s[8];
#pragma unroll
        for (int ct = 0; ct < 8; ++ct) s[ct] = 0.f;
        for (int i = 0; i < nn; ++i) {
            int did = bsrc[(size_t)row * CAP_L + i];
            const float* yp = y_t2 + (size_t)did * HD + l15;
#pragma unroll
            for (int ct = 0; ct < 8; ++ct) s[ct] += yp[ct * 16];
        }
        float part = 0.f;
#pragma unroll
        for (int ct = 0; ct < 8; ++ct) {
            float v = acc[ct][j] + s[ct] * dinv + bv[ct];
            part += fmaxf(v, 0.f) * wpv[ct];
        }
#pragma unroll
        for (int off = 1; off < 16; off <<= 1) part += __shfl_xor(part, off);
        if (valid && l15 == 0) p_l[row] = part;
    }
}

// ---------------------------------------------------------------------------
// K7: out[e] = p_l[src[e]] + p_t[dst[e]] + bp
// ---------------------------------------------------------------------------
__global__ __launch_bounds__(256) void k_out(
    const int* __restrict__ src, const int* __restrict__ dst,
    const float* __restrict__ p_l, const float* __restrict__ p_t,
    const float* __restrict__ bp, float* __restrict__ out)
{
    int e = blockIdx.x * 256 + threadIdx.x;
    if (e >= NEDGE) return;
    out[e] = p_l[src[e]] + p_t[dst[e]] + bp[0];
}

// ---------------------------------------------------------------------------
extern "C" void kernel_launch(void* const* d_in, const int* in_sizes, int n_in,
                              void* d_out, int out_size, void* d_ws, size_t ws_size,
                              hipStream_t stream)
{
    const float* x_l    = (const float*)d_in[0];
    const float* x_t    = (const float*)d_in[1];
    const int*   ei     = (const int*)  d_in[2];
    const float* W1lt_l = (const float*)d_in[3];
    const float* b1lt   = (const float*)d_in[4];
    const float* W1lt_r = (const float*)d_in[5];
    const float* W1tl_l = (const float*)d_in[6];
    const float* b1tl   = (const float*)d_in[7];
    const float* W1tl_r = (const float*)d_in[8];
    const float* W2lt_l = (const float*)d_in[9];
    const float* b2lt   = (const float*)d_in[10];
    const float* W2lt_r = (const float*)d_in[11];
    const float* W2tl_l = (const float*)d_in[12];
    const float* b2tl   = (const float*)d_in[13];
    const float* W2tl_r = (const float*)d_in[14];
    const float* Wp     = (const float*)d_in[15];
    const float* bp     = (const float*)d_in[16];

    const int* src = ei;            // ligand indices
    const int* dst = ei + NEDGE;    // target indices

    char* ws = (char*)d_ws;
    size_t o = 0;
    int* cnt_src = (int*)(ws + o); o += (size_t)N_LIG * 4;
    int* cnt_dst = (int*)(ws + o); o += (size_t)N_TGT * 4;
    int* bsrc = (int*)(ws + o); o += (size_t)N_LIG * CAP_L * 4;
    int* bdst = (int*)(ws + o); o += (size_t)N_TGT * CAP_T * 4;
    uint4* hlbf  = (uint4*)(ws + o);  o += (size_t)NTILE_PAD * 4 * 64 * 16;
    uint4* Wf    = (uint4*)(ws + o);  o += (size_t)32 * 64 * 16;
    uint4* Wf1   = (uint4*)(ws + o);  o += (size_t)640 * 64 * 16;
    uint4* xtf   = (uint4*)(ws + o);  o += (size_t)10000 * 64 * 16;
    float* m_t   = (float*)(ws + o); o += (size_t)N_TGT * 4 * 4;
    float* y_t1  = (float*)(ws + o); o += (size_t)N_TGT * HD * 4;
    float* h_t   = (float*)(ws + o); o += (size_t)N_TGT * HD * 4;
    float* y_t2  = (float*)(ws + o); o += (size_t)N_TGT * HD * 4;
    float* htW2r = (float*)(ws + o); o += (size_t)N_TGT * HD * 4;
    float* p_l   = (float*)(ws + o); o += (size_t)N_LIG * 4;
    float* p_t   = (float*)(ws + o); o += (size_t)N_TGT * 4;

    float* out = (float*)d_out;

    // merged prep: fragment packing + counter zeroing (replaces memset)
    k_pack<<<2770, 256, 0, stream>>>(W2tl_r, Wf, W1lt_r, W1tl_l, Wf1,
                                     x_t, xtf, (int4*)cnt_src);

    k_fill<<<(NEDGE + 255) / 256, 256, 0, stream>>>(src, dst, cnt_src, cnt_dst, bsrc, bdst);
    k_mt<<<(N_TGT * 8) / 256, 256, 0, stream>>>(x_l, bdst, cnt_dst, m_t);

    // conv1
    k_tgt1m<<<N_TGT / 16, 256, 0, stream>>>(xtf, Wf1, m_t, W1lt_l, b1lt, h_t, y_t1);
    k_hl<<<NTILE_L, 256, 0, stream>>>(x_l, y_t1, bsrc, cnt_src, W1tl_r, b1tl, hlbf);

    // conv2 projections on the small (target) side
    k_tgt_gemm2<<<N_TGT / 8, 256, 0, stream>>>(h_t, W2tl_l, W2lt_r, y_t2, htW2r);

    // fused conv2 + predictor
    k_pt<<<N_TGT, 256, 0, stream>>>(hlbf, bdst, cnt_dst, W2lt_l, b2lt, htW2r, Wp, p_t);
    k_pl<<<(NTILE_L + 3) / 4, 256, 0, stream>>>(hlbf, Wf, y_t2, bsrc, cnt_src,
                                                b2tl, Wp, p_l);

    // edges
    k_out<<<(NEDGE + 255) / 256, 256, 0, stream>>>(src, dst, p_l, p_t, bp, out);
}

// Round 8
// 143.584 us; speedup vs baseline: 1.1474x; 1.1474x over previous
//
#include <hip/hip_runtime.h>
#include <hip/hip_bf16.h>

#define N_LIG 100000
#define N_TGT 4000
#define NEDGE 150000
#define DT 1280
#define HD 128
#define CAP_L 32
#define CAP_T 128
#define NTILE_L 6250            // N_LIG / 16
#define NTILE_PAD 6252

typedef __attribute__((ext_vector_type(8))) short short8v;
typedef __attribute__((ext_vector_type(4))) float f32x4;

static __device__ __forceinline__ ushort f2bf(float f) {
    __hip_bfloat16 h = __float2bfloat16(f);
    union { __hip_bfloat16 h; ushort u; } c; c.h = h; return c.u;
}
static __device__ __forceinline__ float bf2f(ushort u) {
    union { unsigned v; float f; } c; c.v = ((unsigned)u) << 16; return c.f;
}

// ---------------------------------------------------------------------------
// K0: merged prep — weight/x_t fragment packing + counter zeroing.
// ---------------------------------------------------------------------------
__global__ __launch_bounds__(256) void k_pack(
    const float* __restrict__ W2, uint4* __restrict__ Wf,
    const float* __restrict__ Wr, const float* __restrict__ Wl,
    uint4* __restrict__ Wf1,
    const float* __restrict__ xt, uint4* __restrict__ xtf,
    int4* __restrict__ cntz)
{
    int bx = blockIdx.x;
    if (bx < 8) {
        int gid = bx * 256 + threadIdx.x;           // 2048
        int lane = gid & 63, frag = gid >> 6;       // frag 0..31
        int ks = frag >> 3, ct = frag & 7;
        int l15 = lane & 15, g = lane >> 4;
        int k = ks * 32 + g * 4, n = ct * 16 + l15;
        union { ushort us[8]; uint4 u; } o;
#pragma unroll
        for (int j = 0; j < 4; ++j) {
            o.us[j]     = f2bf(W2[(size_t)(k + j) * HD + n]);
            o.us[4 + j] = f2bf(W2[(size_t)(k + 16 + j) * HD + n]);
        }
        Wf[gid] = o.u;
    } else if (bx < 168) {
        int gid = (bx - 8) * 256 + threadIdx.x;     // 40960
        int lane = gid & 63, frag = gid >> 6;       // 0..639
        int ks = frag >> 4, nct = frag & 15;
        int l15 = lane & 15, g = lane >> 4;
        int k = ks * 32 + g * 4, n = nct * 16 + l15;
        const float* Ws = (n < HD) ? Wr : Wl;
        int nn = n & 127;
        union { ushort us[8]; uint4 u; } o;
#pragma unroll
        for (int j = 0; j < 4; ++j) {
            o.us[j]     = f2bf(Ws[(size_t)(k + j) * HD + nn]);
            o.us[4 + j] = f2bf(Ws[(size_t)(k + 16 + j) * HD + nn]);
        }
        Wf1[gid] = o.u;
    } else if (bx < 2668) {
        int gid = (bx - 168) * 256 + threadIdx.x;   // 640000
        int lane = gid & 63, frag = gid >> 6;       // 0..9999
        int ks = frag % 40, rt = frag / 40;
        int row = rt * 16 + (lane & 15);
        int kb = ks * 32 + (lane >> 4) * 4;
        float4 a0 = *reinterpret_cast<const float4*>(xt + (size_t)row * DT + kb);
        float4 a1 = *reinterpret_cast<const float4*>(xt + (size_t)row * DT + kb + 16);
        union { ushort us[8]; uint4 u; } o;
        o.us[0] = f2bf(a0.x); o.us[1] = f2bf(a0.y); o.us[2] = f2bf(a0.z); o.us[3] = f2bf(a0.w);
        o.us[4] = f2bf(a1.x); o.us[5] = f2bf(a1.y); o.us[6] = f2bf(a1.z); o.us[7] = f2bf(a1.w);
        xtf[gid] = o.u;
    } else {
        int i = (bx - 2668) * 256 + threadIdx.x;
        if (i < 26000) cntz[i] = make_int4(0, 0, 0, 0);
    }
}

// ---------------------------------------------------------------------------
// K1: build adjacency buckets (int atomics only).
// ---------------------------------------------------------------------------
__global__ __launch_bounds__(256) void k_fill(
    const int* __restrict__ src, const int* __restrict__ dst,
    int* __restrict__ cnt_src, int* __restrict__ cnt_dst,
    int* __restrict__ bsrc, int* __restrict__ bdst)
{
    int e = blockIdx.x * 256 + threadIdx.x;
    if (e >= NEDGE) return;
    int s = src[e], d = dst[e];
    int ps = atomicAdd(&cnt_src[s], 1);
    if (ps < CAP_L) bsrc[(size_t)s * CAP_L + ps] = d;
    int pd = atomicAdd(&cnt_dst[d], 1);
    if (pd < CAP_T) bdst[(size_t)d * CAP_T + pd] = s;
}

// ---------------------------------------------------------------------------
// K1d: m_t[t][0..3] = mean_{src in bucket} x_l[src]
// ---------------------------------------------------------------------------
__global__ __launch_bounds__(256) void k_mt(
    const float* __restrict__ xl,
    const int* __restrict__ bdst, const int* __restrict__ cnt_dst,
    float* __restrict__ m_t)
{
    int t = blockIdx.x * 256 + threadIdx.x;
    int row = t >> 3, lane8 = t & 7;
    if (row >= N_TGT) return;
    int deg = cnt_dst[row];
    int n = min(deg, CAP_T);
    float4 acc = make_float4(0.f, 0.f, 0.f, 0.f);
    for (int i = lane8; i < n; i += 8) {
        int sid = bdst[(size_t)row * CAP_T + i];
        float4 x = *reinterpret_cast<const float4*>(xl + 4ull * (unsigned)sid);
        acc.x += x.x; acc.y += x.y; acc.z += x.z; acc.w += x.w;
    }
#pragma unroll
    for (int off = 1; off < 8; off <<= 1) {
        acc.x += __shfl_xor(acc.x, off); acc.y += __shfl_xor(acc.y, off);
        acc.z += __shfl_xor(acc.z, off); acc.w += __shfl_xor(acc.w, off);
    }
    if (lane8 == 0) {
        float dinv = 1.0f / fmaxf((float)deg, 1.0f);
        float4 o = make_float4(acc.x * dinv, acc.y * dinv, acc.z * dinv, acc.w * dinv);
        *reinterpret_cast<float4*>(m_t + 4 * row) = o;
    }
}

// ---------------------------------------------------------------------------
// K2: MFMA target conv1 — all operand loads 16B coalesced from packed frags.
// ---------------------------------------------------------------------------
__global__ __launch_bounds__(256) void k_tgt1m(
    const uint4* __restrict__ xtf,    // [250*40][64] bf16 A-frags
    const uint4* __restrict__ Wf1,    // [640][64] bf16 B-frags
    const float* __restrict__ m_t,    // [4000,4]
    const float* __restrict__ W1lt_l, // [4,128]
    const float* __restrict__ b1lt,
    float* __restrict__ h_t, float* __restrict__ y_t1)
{
    int w = threadIdx.x >> 6;
    int lane = threadIdx.x & 63;
    int l15 = lane & 15, g = lane >> 4;
    int rt = blockIdx.x;
    int row0 = rt * 16;
    int cb = w * 64;

    f32x4 acc[4];
#pragma unroll
    for (int ct = 0; ct < 4; ++ct) acc[ct] = (f32x4){0.f, 0.f, 0.f, 0.f};

    for (int ks = 0; ks < DT / 32; ++ks) {
        union { uint4 u; short8v s; } ua;
        ua.u = xtf[(size_t)(rt * 40 + ks) * 64 + lane];
#pragma unroll
        for (int ct = 0; ct < 4; ++ct) {
            int nct = w * 4 + ct;
            union { uint4 u; short8v s; } ub;
            ub.u = Wf1[(size_t)(ks * 16 + nct) * 64 + lane];
            acc[ct] = __builtin_amdgcn_mfma_f32_16x16x32_bf16(ua.s, ub.s, acc[ct], 0, 0, 0);
        }
    }

    if (w < 2) {
#pragma unroll
        for (int ct = 0; ct < 4; ++ct) {
            int c = cb + ct * 16 + l15;
            float wl0 = W1lt_l[c], wl1 = W1lt_l[HD + c],
                  wl2 = W1lt_l[2 * HD + c], wl3 = W1lt_l[3 * HD + c];
            float bb = b1lt[c];
#pragma unroll
            for (int j = 0; j < 4; ++j) {
                int grow = row0 + 4 * g + j;
                float4 m = *reinterpret_cast<const float4*>(m_t + 4 * grow);
                float v = acc[ct][j] + bb + m.x * wl0 + m.y * wl1 + m.z * wl2 + m.w * wl3;
                h_t[(size_t)grow * HD + c] = fmaxf(v, 0.0f);
            }
        }
    } else {
#pragma unroll
        for (int ct = 0; ct < 4; ++ct) {
            int c = cb - HD + ct * 16 + l15;
#pragma unroll
            for (int j = 0; j < 4; ++j) {
                int grow = row0 + 4 * g + j;
                y_t1[(size_t)grow * HD + c] = acc[ct][j];
            }
        }
    }
}

// ---------------------------------------------------------------------------
// K3: fused ligand conv1 -> hlb (row layout, for k_pt) + hlbf (fragment
// layout, for k_pl). Block = 16 nodes; 16 threads/node; thread tc=(ks,g).
// ---------------------------------------------------------------------------
__global__ __launch_bounds__(256) void k_hl(
    const float* __restrict__ xl, const float* __restrict__ y_t1,
    const int* __restrict__ bsrc, const int* __restrict__ cnt_src,
    const float* __restrict__ W1tl_r,  // [4,128]
    const float* __restrict__ b1tl,
    ushort* __restrict__ hlb, uint4* __restrict__ hlbf)
{
    int tc = threadIdx.x & 15;
    int node = blockIdx.x * 16 + (threadIdx.x >> 4);
    int ks = tc >> 2, g = tc & 3;
    int kb = ks * 32 + g * 4;

    int deg = cnt_src[node];
    int n = min(deg, CAP_L);
    float4 s0 = make_float4(0.f, 0.f, 0.f, 0.f);
    float4 s1 = make_float4(0.f, 0.f, 0.f, 0.f);
    for (int i = 0; i < n; ++i) {
        int did = bsrc[(size_t)node * CAP_L + i];
        float4 v0 = *reinterpret_cast<const float4*>(y_t1 + (size_t)did * HD + kb);
        float4 v1 = *reinterpret_cast<const float4*>(y_t1 + (size_t)did * HD + kb + 16);
        s0.x += v0.x; s0.y += v0.y; s0.z += v0.z; s0.w += v0.w;
        s1.x += v1.x; s1.y += v1.y; s1.z += v1.z; s1.w += v1.w;
    }
    float dinv = 1.0f / fmaxf((float)deg, 1.0f);
    float4 x = *reinterpret_cast<const float4*>(xl + 4ull * (unsigned)node);

    float4 b0 = *reinterpret_cast<const float4*>(b1tl + kb);
    float4 b1 = *reinterpret_cast<const float4*>(b1tl + kb + 16);
    float4 wa0 = *reinterpret_cast<const float4*>(W1tl_r + 0 * HD + kb);
    float4 wa1 = *reinterpret_cast<const float4*>(W1tl_r + 1 * HD + kb);
    float4 wa2 = *reinterpret_cast<const float4*>(W1tl_r + 2 * HD + kb);
    float4 wa3 = *reinterpret_cast<const float4*>(W1tl_r + 3 * HD + kb);
    float4 wb0 = *reinterpret_cast<const float4*>(W1tl_r + 0 * HD + kb + 16);
    float4 wb1 = *reinterpret_cast<const float4*>(W1tl_r + 1 * HD + kb + 16);
    float4 wb2 = *reinterpret_cast<const float4*>(W1tl_r + 2 * HD + kb + 16);
    float4 wb3 = *reinterpret_cast<const float4*>(W1tl_r + 3 * HD + kb + 16);

    union { ushort us[8]; uint4 u; ushort4 h[2]; } o;
    o.us[0] = f2bf(fmaxf(s0.x * dinv + b0.x + x.x * wa0.x + x.y * wa1.x + x.z * wa2.x + x.w * wa3.x, 0.f));
    o.us[1] = f2bf(fmaxf(s0.y * dinv + b0.y + x.x * wa0.y + x.y * wa1.y + x.z * wa2.y + x.w * wa3.y, 0.f));
    o.us[2] = f2bf(fmaxf(s0.z * dinv + b0.z + x.x * wa0.z + x.y * wa1.z + x.z * wa2.z + x.w * wa3.z, 0.f));
    o.us[3] = f2bf(fmaxf(s0.w * dinv + b0.w + x.x * wa0.w + x.y * wa1.w + x.z * wa2.w + x.w * wa3.w, 0.f));
    o.us[4] = f2bf(fmaxf(s1.x * dinv + b1.x + x.x * wb0.x + x.y * wb1.x + x.z * wb2.x + x.w * wb3.x, 0.f));
    o.us[5] = f2bf(fmaxf(s1.y * dinv + b1.y + x.x * wb0.y + x.y * wb1.y + x.z * wb2.y + x.w * wb3.y, 0.f));
    o.us[6] = f2bf(fmaxf(s1.z * dinv + b1.z + x.x * wb0.z + x.y * wb1.z + x.z * wb2.z + x.w * wb3.z, 0.f));
    o.us[7] = f2bf(fmaxf(s1.w * dinv + b1.w + x.x * wb0.w + x.y * wb1.w + x.z * wb2.w + x.w * wb3.w, 0.f));

    *reinterpret_cast<ushort4*>(hlb + (size_t)node * HD + kb)      = o.h[0];
    *reinterpret_cast<ushort4*>(hlb + (size_t)node * HD + kb + 16) = o.h[1];
    int lane = (node & 15) + 16 * g;
    hlbf[(size_t)(blockIdx.x * 4 + ks) * 64 + lane] = o.u;
}

// ---------------------------------------------------------------------------
// K4: h_t [4000,128] @ {W2tl_l, W2lt_r} -> y_t2, htW2r
// ---------------------------------------------------------------------------
__global__ __launch_bounds__(256) void k_tgt_gemm2(
    const float* __restrict__ ht,
    const float* __restrict__ Wl,   // W2tl_l [128,128]
    const float* __restrict__ Wr,   // W2lt_r [128,128]
    float* __restrict__ y_t2,
    float* __restrict__ htW2r)
{
    __shared__ float xs[8][HD];
    int row0 = blockIdx.x * 8;
    const float4* srcv = reinterpret_cast<const float4*>(ht + (size_t)row0 * HD);
    float4* dstv = reinterpret_cast<float4*>(&xs[0][0]);
    for (int i = threadIdx.x; i < 8 * HD / 4; i += 256) dstv[i] = srcv[i];
    __syncthreads();

    int n = threadIdx.x;
    const float* W = (n < HD) ? (Wl + n) : (Wr + (n - HD));
    float acc[8] = {0.f,0.f,0.f,0.f,0.f,0.f,0.f,0.f};
    for (int k = 0; k < HD; k += 4) {
        float w0 = W[(size_t)(k + 0) * HD];
        float w1 = W[(size_t)(k + 1) * HD];
        float w2 = W[(size_t)(k + 2) * HD];
        float w3 = W[(size_t)(k + 3) * HD];
#pragma unroll
        for (int r = 0; r < 8; ++r) {
            float4 a = *reinterpret_cast<const float4*>(&xs[r][k]);
            acc[r] += a.x * w0 + a.y * w1 + a.z * w2 + a.w * w3;
        }
    }
    float* o = (n < HD) ? (y_t2 + (size_t)row0 * HD + n)
                        : (htW2r + (size_t)row0 * HD + (n - HD));
#pragma unroll
    for (int r = 0; r < 8; ++r) o[(size_t)r * HD] = acc[r];
}

// ---------------------------------------------------------------------------
// K5: fused target conv2 + predictor — coalesced row gather from hlb
// (8 groups x 32 lanes, ushort4 per lane = contiguous 256B per neighbor),
// LDS reduce, then 128-thread GEMM column phase.
// ---------------------------------------------------------------------------
__global__ __launch_bounds__(256) void k_pt(
    const ushort* __restrict__ hlb,
    const int* __restrict__ bdst, const int* __restrict__ cnt_dst,
    const float* __restrict__ W,    // W2lt_l [128,128]
    const float* __restrict__ b,    // b2lt
    const float* __restrict__ htW2r,
    const float* __restrict__ Wp,   // [256]
    float* __restrict__ p_t)
{
    __shared__ float sm[8][HD];
    __shared__ float msh[HD];
    __shared__ float sum2[2];
    int row = blockIdx.x;
    int wg = threadIdx.x >> 5, c = threadIdx.x & 31;
    int deg = cnt_dst[row];
    int nn = min(deg, CAP_T);

    float4 s = make_float4(0.f, 0.f, 0.f, 0.f);
    for (int i = wg; i < nn; i += 8) {
        int sid = bdst[(size_t)row * CAP_T + i];
        ushort4 v = *reinterpret_cast<const ushort4*>(hlb + (size_t)sid * HD + c * 4);
        s.x += bf2f(v.x); s.y += bf2f(v.y); s.z += bf2f(v.z); s.w += bf2f(v.w);
    }
    *reinterpret_cast<float4*>(&sm[wg][c * 4]) = s;
    __syncthreads();

    if (threadIdx.x < HD) {
        int h = threadIdx.x;
        float dinv = 1.0f / fmaxf((float)deg, 1.0f);
        float acc = sm[0][h] + sm[1][h] + sm[2][h] + sm[3][h]
                  + sm[4][h] + sm[5][h] + sm[6][h] + sm[7][h];
        msh[h] = acc * dinv;
    }
    __syncthreads();

    if (threadIdx.x < HD) {
        int h = threadIdx.x;
        float g = 0.f;
        for (int k = 0; k < HD; k += 4) {
            float4 mk = *reinterpret_cast<const float4*>(&msh[k]);
            g += mk.x * W[(size_t)(k + 0) * HD + h] + mk.y * W[(size_t)(k + 1) * HD + h]
               + mk.z * W[(size_t)(k + 2) * HD + h] + mk.w * W[(size_t)(k + 3) * HD + h];
        }
        float v = fmaxf(g + b[h] + htW2r[(size_t)row * HD + h], 0.0f);
        float part = v * Wp[HD + h];
#pragma unroll
        for (int off = 1; off < 64; off <<= 1) part += __shfl_xor(part, off);
        if ((h & 63) == 0) sum2[h >> 6] = part;
    }
    __syncthreads();
    if (threadIdx.x == 0) p_t[row] = sum2[0] + sum2[1];
}

// ---------------------------------------------------------------------------
// K6: ligand conv2 + predictor via MFMA; fused y_t2 neighbor-mean epilogue.
// ---------------------------------------------------------------------------
__global__ __launch_bounds__(256) void k_pl(
    const uint4* __restrict__ hlbf,   // [NTILE_PAD*4][64] A-frags
    const uint4* __restrict__ Wf,     // [32][64] B-frags
    const float* __restrict__ y_t2,
    const int* __restrict__ bsrc, const int* __restrict__ cnt_src,
    const float* __restrict__ b,      // b2tl
    const float* __restrict__ Wp,     // [256]; ligand part = Wp[0..127]
    float* __restrict__ p_l)
{
    int wid = threadIdx.x >> 6;
    int lane = threadIdx.x & 63;
    int l15 = lane & 15, g = lane >> 4;
    int tile = blockIdx.x * 4 + wid;
    int wrow0 = tile * 16;

    f32x4 acc[8];
#pragma unroll
    for (int ct = 0; ct < 8; ++ct) acc[ct] = (f32x4){0.f, 0.f, 0.f, 0.f};

#pragma unroll
    for (int ks = 0; ks < 4; ++ks) {
        union { uint4 u; short8v s; } ua;
        ua.u = hlbf[(size_t)(tile * 4 + ks) * 64 + lane];
#pragma unroll
        for (int ct = 0; ct < 8; ++ct) {
            union { uint4 u; short8v s; } ub;
            ub.u = Wf[(ks * 8 + ct) * 64 + lane];
            acc[ct] = __builtin_amdgcn_mfma_f32_16x16x32_bf16(ua.s, ub.s, acc[ct], 0, 0, 0);
        }
    }

    float wpv[8], bv[8];
#pragma unroll
    for (int ct = 0; ct < 8; ++ct) {
        int c = ct * 16 + l15;
        wpv[ct] = Wp[c];
        bv[ct]  = b[c];
    }

#pragma unroll
    for (int j = 0; j < 4; ++j) {
        int row = wrow0 + g * 4 + j;
        bool valid = row < N_LIG;
        int deg = valid ? cnt_src[row] : 0;
        int nn = min(deg, CAP_L);
        float dinv = 1.0f / fmaxf((float)deg, 1.0f);
        float s[8];
#pragma unroll
        for (int ct = 0; ct < 8; ++ct) s[ct] = 0.f;
        for (int i = 0; i < nn; ++i) {
            int did = bsrc[(size_t)row * CAP_L + i];
            const float* yp = y_t2 + (size_t)did * HD + l15;
#pragma unroll
            for (int ct = 0; ct < 8; ++ct) s[ct] += yp[ct * 16];
        }
        float part = 0.f;
#pragma unroll
        for (int ct = 0; ct < 8; ++ct) {
            float v = acc[ct][j] + s[ct] * dinv + bv[ct];
            part += fmaxf(v, 0.f) * wpv[ct];
        }
#pragma unroll
        for (int off = 1; off < 16; off <<= 1) part += __shfl_xor(part, off);
        if (valid && l15 == 0) p_l[row] = part;
    }
}

// ---------------------------------------------------------------------------
// K7: out[e] = p_l[src[e]] + p_t[dst[e]] + bp
// ---------------------------------------------------------------------------
__global__ __launch_bounds__(256) void k_out(
    const int* __restrict__ src, const int* __restrict__ dst,
    const float* __restrict__ p_l, const float* __restrict__ p_t,
    const float* __restrict__ bp, float* __restrict__ out)
{
    int e = blockIdx.x * 256 + threadIdx.x;
    if (e >= NEDGE) return;
    out[e] = p_l[src[e]] + p_t[dst[e]] + bp[0];
}

// ---------------------------------------------------------------------------
extern "C" void kernel_launch(void* const* d_in, const int* in_sizes, int n_in,
                              void* d_out, int out_size, void* d_ws, size_t ws_size,
                              hipStream_t stream)
{
    const float* x_l    = (const float*)d_in[0];
    const float* x_t    = (const float*)d_in[1];
    const int*   ei     = (const int*)  d_in[2];
    const float* W1lt_l = (const float*)d_in[3];
    const float* b1lt   = (const float*)d_in[4];
    const float* W1lt_r = (const float*)d_in[5];
    const float* W1tl_l = (const float*)d_in[6];
    const float* b1tl   = (const float*)d_in[7];
    const float* W1tl_r = (const float*)d_in[8];
    const float* W2lt_l = (const float*)d_in[9];
    const float* b2lt   = (const float*)d_in[10];
    const float* W2lt_r = (const float*)d_in[11];
    const float* W2tl_l = (const float*)d_in[12];
    const float* b2tl   = (const float*)d_in[13];
    const float* W2tl_r = (const float*)d_in[14];
    const float* Wp     = (const float*)d_in[15];
    const float* bp     = (const float*)d_in[16];

    const int* src = ei;            // ligand indices
    const int* dst = ei + NEDGE;    // target indices

    char* ws = (char*)d_ws;
    size_t o = 0;
    int* cnt_src = (int*)(ws + o); o += (size_t)N_LIG * 4;
    int* cnt_dst = (int*)(ws + o); o += (size_t)N_TGT * 4;
    int* bsrc = (int*)(ws + o); o += (size_t)N_LIG * CAP_L * 4;
    int* bdst = (int*)(ws + o); o += (size_t)N_TGT * CAP_T * 4;
    ushort* hlb  = (ushort*)(ws + o); o += (size_t)N_LIG * HD * 2;
    uint4* hlbf  = (uint4*)(ws + o);  o += (size_t)NTILE_PAD * 4 * 64 * 16;
    uint4* Wf    = (uint4*)(ws + o);  o += (size_t)32 * 64 * 16;
    uint4* Wf1   = (uint4*)(ws + o);  o += (size_t)640 * 64 * 16;
    uint4* xtf   = (uint4*)(ws + o);  o += (size_t)10000 * 64 * 16;
    float* m_t   = (float*)(ws + o); o += (size_t)N_TGT * 4 * 4;
    float* y_t1  = (float*)(ws + o); o += (size_t)N_TGT * HD * 4;
    float* h_t   = (float*)(ws + o); o += (size_t)N_TGT * HD * 4;
    float* y_t2  = (float*)(ws + o); o += (size_t)N_TGT * HD * 4;
    float* htW2r = (float*)(ws + o); o += (size_t)N_TGT * HD * 4;
    float* p_l   = (float*)(ws + o); o += (size_t)N_LIG * 4;
    float* p_t   = (float*)(ws + o); o += (size_t)N_TGT * 4;

    float* out = (float*)d_out;

    // merged prep: fragment packing + counter zeroing (replaces memset)
    k_pack<<<2770, 256, 0, stream>>>(W2tl_r, Wf, W1lt_r, W1tl_l, Wf1,
                                     x_t, xtf, (int4*)cnt_src);

    k_fill<<<(NEDGE + 255) / 256, 256, 0, stream>>>(src, dst, cnt_src, cnt_dst, bsrc, bdst);
    k_mt<<<(N_TGT * 8) / 256, 256, 0, stream>>>(x_l, bdst, cnt_dst, m_t);

    // conv1
    k_tgt1m<<<N_TGT / 16, 256, 0, stream>>>(xtf, Wf1, m_t, W1lt_l, b1lt, h_t, y_t1);
    k_hl<<<NTILE_L, 256, 0, stream>>>(x_l, y_t1, bsrc, cnt_src, W1tl_r, b1tl, hlb, hlbf);

    // conv2 projections on the small (target) side
    k_tgt_gemm2<<<N_TGT / 8, 256, 0, stream>>>(h_t, W2tl_l, W2lt_r, y_t2, htW2r);

    // fused conv2 + predictor
    k_pt<<<N_TGT, 256, 0, stream>>>(hlb, bdst, cnt_dst, W2lt_l, b2lt, htW2r, Wp, p_t);
    k_pl<<<(NTILE_L + 3) / 4, 256, 0, stream>>>(hlbf, Wf, y_t2, bsrc, cnt_src,
                                                b2tl, Wp, p_l);

    // edges
    k_out<<<(NEDGE + 255) / 256, 256, 0, stream>>>(src, dst, p_l, p_t, bp, out);
}

// Round 9
// 136.601 us; speedup vs baseline: 1.2060x; 1.0511x over previous
//
#include <hip/hip_runtime.h>
#include <hip/hip_bf16.h>

#define N_LIG 100000
#define N_TGT 4000
#define NEDGE 150000
#define DT 1280
#define HD 128
#define CAP_L 32
#define CAP_T 128
#define NTILE_L 6250            // N_LIG / 16
#define NTILE_PAD 6252
#define PL_BLOCKS 1563          // ceil(NTILE_L/4)

typedef __attribute__((ext_vector_type(8))) short short8v;
typedef __attribute__((ext_vector_type(4))) float f32x4;

static __device__ __forceinline__ ushort f2bf(float f) {
    __hip_bfloat16 h = __float2bfloat16(f);
    union { __hip_bfloat16 h; ushort u; } c; c.h = h; return c.u;
}
static __device__ __forceinline__ float bf2f(ushort u) {
    union { unsigned v; float f; } c; c.v = ((unsigned)u) << 16; return c.f;
}

// ---------------------------------------------------------------------------
// K0: merged prep — fragment packing for all MFMA operands + counter zeroing.
//   [0,8):      Wf  = W2tl_r B-frags
//   [8,168):    Wf1 = {W1lt_r|W1tl_l} B-frags (256 cols, K=1280)
//   [168,2668): xtf = x_t bf16 A-frags
//   [2668,2770): zero cnt_src/cnt_dst
//   [2770,2786): Wf2 = {W2tl_l|W2lt_r} B-frags (256 cols, K=128)
// ---------------------------------------------------------------------------
__global__ __launch_bounds__(256) void k_pack(
    const float* __restrict__ W2, uint4* __restrict__ Wf,
    const float* __restrict__ Wr, const float* __restrict__ Wl,
    uint4* __restrict__ Wf1,
    const float* __restrict__ xt, uint4* __restrict__ xtf,
    int4* __restrict__ cntz,
    const float* __restrict__ W2a, const float* __restrict__ W2b,
    uint4* __restrict__ Wf2)
{
    int bx = blockIdx.x;
    if (bx < 8) {
        int gid = bx * 256 + threadIdx.x;           // 2048
        int lane = gid & 63, frag = gid >> 6;       // frag 0..31
        int ks = frag >> 3, ct = frag & 7;
        int l15 = lane & 15, g = lane >> 4;
        int k = ks * 32 + g * 4, n = ct * 16 + l15;
        union { ushort us[8]; uint4 u; } o;
#pragma unroll
        for (int j = 0; j < 4; ++j) {
            o.us[j]     = f2bf(W2[(size_t)(k + j) * HD + n]);
            o.us[4 + j] = f2bf(W2[(size_t)(k + 16 + j) * HD + n]);
        }
        Wf[gid] = o.u;
    } else if (bx < 168) {
        int gid = (bx - 8) * 256 + threadIdx.x;     // 40960
        int lane = gid & 63, frag = gid >> 6;       // 0..639
        int ks = frag >> 4, nct = frag & 15;
        int l15 = lane & 15, g = lane >> 4;
        int k = ks * 32 + g * 4, n = nct * 16 + l15;
        const float* Ws = (n < HD) ? Wr : Wl;
        int nn = n & 127;
        union { ushort us[8]; uint4 u; } o;
#pragma unroll
        for (int j = 0; j < 4; ++j) {
            o.us[j]     = f2bf(Ws[(size_t)(k + j) * HD + nn]);
            o.us[4 + j] = f2bf(Ws[(size_t)(k + 16 + j) * HD + nn]);
        }
        Wf1[gid] = o.u;
    } else if (bx < 2668) {
        int gid = (bx - 168) * 256 + threadIdx.x;   // 640000
        int lane = gid & 63, frag = gid >> 6;       // 0..9999
        int ks = frag % 40, rt = frag / 40;
        int row = rt * 16 + (lane & 15);
        int kb = ks * 32 + (lane >> 4) * 4;
        float4 a0 = *reinterpret_cast<const float4*>(xt + (size_t)row * DT + kb);
        float4 a1 = *reinterpret_cast<const float4*>(xt + (size_t)row * DT + kb + 16);
        union { ushort us[8]; uint4 u; } o;
        o.us[0] = f2bf(a0.x); o.us[1] = f2bf(a0.y); o.us[2] = f2bf(a0.z); o.us[3] = f2bf(a0.w);
        o.us[4] = f2bf(a1.x); o.us[5] = f2bf(a1.y); o.us[6] = f2bf(a1.z); o.us[7] = f2bf(a1.w);
        xtf[gid] = o.u;
    } else if (bx < 2770) {
        int i = (bx - 2668) * 256 + threadIdx.x;
        if (i < 26000) cntz[i] = make_int4(0, 0, 0, 0);
    } else {
        int gid = (bx - 2770) * 256 + threadIdx.x;  // 4096
        int lane = gid & 63, frag = gid >> 6;       // 0..63
        int ks = frag >> 4, nct = frag & 15;
        int l15 = lane & 15, g = lane >> 4;
        int k = ks * 32 + g * 4, n = nct * 16 + l15;
        const float* Ws = (n < HD) ? W2a : W2b;
        int nn = n & 127;
        union { ushort us[8]; uint4 u; } o;
#pragma unroll
        for (int j = 0; j < 4; ++j) {
            o.us[j]     = f2bf(Ws[(size_t)(k + j) * HD + nn]);
            o.us[4 + j] = f2bf(Ws[(size_t)(k + 16 + j) * HD + nn]);
        }
        Wf2[gid] = o.u;
    }
}

// ---------------------------------------------------------------------------
// K1: build adjacency buckets (int atomics only).
// ---------------------------------------------------------------------------
__global__ __launch_bounds__(256) void k_fill(
    const int* __restrict__ src, const int* __restrict__ dst,
    int* __restrict__ cnt_src, int* __restrict__ cnt_dst,
    int* __restrict__ bsrc, int* __restrict__ bdst)
{
    int e = blockIdx.x * 256 + threadIdx.x;
    if (e >= NEDGE) return;
    int s = src[e], d = dst[e];
    int ps = atomicAdd(&cnt_src[s], 1);
    if (ps < CAP_L) bsrc[(size_t)s * CAP_L + ps] = d;
    int pd = atomicAdd(&cnt_dst[d], 1);
    if (pd < CAP_T) bdst[(size_t)d * CAP_T + pd] = s;
}

// ---------------------------------------------------------------------------
// K2: fully fused target pipeline (conv1 GEMM + m_t gather + conv2 GEMM).
//   phase A: m_t = mean(x_l[nbr]) into LDS (threads 0..127, 8/row)
//   phase B: D = x_t @ {W1lt_r|W1tl_l} via MFMA (K=1280)
//   phase C: h_t = relu(D + b + m·W1lt_l) -> LDS bf16; y_t1 = D -> global
//   phase D: {y_t2|htW2r} = h_t @ {W2tl_l|W2lt_r} via MFMA (K=128) -> global
// ---------------------------------------------------------------------------
__global__ __launch_bounds__(256) void k_tgt1m(
    const uint4* __restrict__ xtf,    // [250*40][64] bf16 A-frags
    const uint4* __restrict__ Wf1,    // [640][64] bf16 B-frags
    const uint4* __restrict__ Wf2,    // [64][64] bf16 B-frags (conv2)
    const float* __restrict__ xl,
    const int* __restrict__ bdst, const int* __restrict__ cnt_dst,
    const float* __restrict__ W1lt_l, // [4,128]
    const float* __restrict__ b1lt,
    float* __restrict__ y_t1,
    float* __restrict__ y_t2, float* __restrict__ htW2r)
{
    __shared__ float  ms[16][4];
    __shared__ ushort hts[16][136];   // padded: row stride 272B -> 2-way max

    int w = threadIdx.x >> 6;
    int lane = threadIdx.x & 63;
    int l15 = lane & 15, g = lane >> 4;
    int rt = blockIdx.x;
    int row0 = rt * 16;
    int cb = w * 64;

    // phase A: neighbor mean of x_l (4-dim), threads 0..127
    if (threadIdx.x < 128) {
        int r = threadIdx.x >> 3, lane8 = threadIdx.x & 7;
        int row = row0 + r;
        int deg = cnt_dst[row];
        int n = min(deg, CAP_T);
        float4 acc = make_float4(0.f, 0.f, 0.f, 0.f);
        for (int i = lane8; i < n; i += 8) {
            int sid = bdst[(size_t)row * CAP_T + i];
            float4 x = *reinterpret_cast<const float4*>(xl + 4ull * (unsigned)sid);
            acc.x += x.x; acc.y += x.y; acc.z += x.z; acc.w += x.w;
        }
#pragma unroll
        for (int off = 1; off < 8; off <<= 1) {
            acc.x += __shfl_xor(acc.x, off); acc.y += __shfl_xor(acc.y, off);
            acc.z += __shfl_xor(acc.z, off); acc.w += __shfl_xor(acc.w, off);
        }
        if (lane8 == 0) {
            float dinv = 1.0f / fmaxf((float)deg, 1.0f);
            ms[r][0] = acc.x * dinv; ms[r][1] = acc.y * dinv;
            ms[r][2] = acc.z * dinv; ms[r][3] = acc.w * dinv;
        }
    }

    // phase B: conv1 MFMA K-loop
    f32x4 acc[4];
#pragma unroll
    for (int ct = 0; ct < 4; ++ct) acc[ct] = (f32x4){0.f, 0.f, 0.f, 0.f};

    for (int ks = 0; ks < DT / 32; ++ks) {
        union { uint4 u; short8v s; } ua;
        ua.u = xtf[(size_t)(rt * 40 + ks) * 64 + lane];
#pragma unroll
        for (int ct = 0; ct < 4; ++ct) {
            union { uint4 u; short8v s; } ub;
            ub.u = Wf1[(size_t)(ks * 16 + w * 4 + ct) * 64 + lane];
            acc[ct] = __builtin_amdgcn_mfma_f32_16x16x32_bf16(ua.s, ub.s, acc[ct], 0, 0, 0);
        }
    }

    __syncthreads();   // ms visible to waves 0-1

    // phase C: epilogue — h_t into LDS bf16 (waves 0-1), y_t1 to global (2-3)
    if (w < 2) {
#pragma unroll
        for (int ct = 0; ct < 4; ++ct) {
            int c = cb + ct * 16 + l15;
            float wl0 = W1lt_l[c], wl1 = W1lt_l[HD + c],
                  wl2 = W1lt_l[2 * HD + c], wl3 = W1lt_l[3 * HD + c];
            float bb = b1lt[c];
#pragma unroll
            for (int j = 0; j < 4; ++j) {
                int r = 4 * g + j;
                float v = acc[ct][j] + bb + ms[r][0] * wl0 + ms[r][1] * wl1
                        + ms[r][2] * wl2 + ms[r][3] * wl3;
                hts[r][c] = f2bf(fmaxf(v, 0.0f));
            }
        }
    } else {
#pragma unroll
        for (int ct = 0; ct < 4; ++ct) {
            int c = cb - HD + ct * 16 + l15;
#pragma unroll
            for (int j = 0; j < 4; ++j) {
                int grow = row0 + 4 * g + j;
                y_t1[(size_t)grow * HD + c] = acc[ct][j];
            }
        }
    }
    __syncthreads();

    // phase D: conv2 MFMA (K=128) from LDS h_t
    f32x4 acc2[4];
#pragma unroll
    for (int ct = 0; ct < 4; ++ct) acc2[ct] = (f32x4){0.f, 0.f, 0.f, 0.f};

#pragma unroll
    for (int ks2 = 0; ks2 < 4; ++ks2) {
        int kb2 = ks2 * 32 + g * 4;
        union { ushort us[8]; short8v s; } ua2;
        *reinterpret_cast<ushort4*>(&ua2.us[0]) =
            *reinterpret_cast<const ushort4*>(&hts[l15][kb2]);
        *reinterpret_cast<ushort4*>(&ua2.us[4]) =
            *reinterpret_cast<const ushort4*>(&hts[l15][kb2 + 16]);
#pragma unroll
        for (int ct = 0; ct < 4; ++ct) {
            union { uint4 u; short8v s; } ub2;
            ub2.u = Wf2[(size_t)(ks2 * 16 + w * 4 + ct) * 64 + lane];
            acc2[ct] = __builtin_amdgcn_mfma_f32_16x16x32_bf16(ua2.s, ub2.s, acc2[ct], 0, 0, 0);
        }
    }

    float* outp = (w < 2) ? y_t2 : htW2r;
    int cb2 = (w < 2) ? cb : (cb - HD);
#pragma unroll
    for (int ct = 0; ct < 4; ++ct) {
        int c = cb2 + ct * 16 + l15;
#pragma unroll
        for (int j = 0; j < 4; ++j) {
            int grow = row0 + 4 * g + j;
            outp[(size_t)grow * HD + c] = acc2[ct][j];
        }
    }
}

// ---------------------------------------------------------------------------
// K3: fused ligand conv1 -> hlb (row layout) + hlbf (fragment layout).
// ---------------------------------------------------------------------------
__global__ __launch_bounds__(256) void k_hl(
    const float* __restrict__ xl, const float* __restrict__ y_t1,
    const int* __restrict__ bsrc, const int* __restrict__ cnt_src,
    const float* __restrict__ W1tl_r,  // [4,128]
    const float* __restrict__ b1tl,
    ushort* __restrict__ hlb, uint4* __restrict__ hlbf)
{
    int tc = threadIdx.x & 15;
    int node = blockIdx.x * 16 + (threadIdx.x >> 4);
    int ks = tc >> 2, g = tc & 3;
    int kb = ks * 32 + g * 4;

    int deg = cnt_src[node];
    int n = min(deg, CAP_L);
    float4 s0 = make_float4(0.f, 0.f, 0.f, 0.f);
    float4 s1 = make_float4(0.f, 0.f, 0.f, 0.f);
    for (int i = 0; i < n; ++i) {
        int did = bsrc[(size_t)node * CAP_L + i];
        float4 v0 = *reinterpret_cast<const float4*>(y_t1 + (size_t)did * HD + kb);
        float4 v1 = *reinterpret_cast<const float4*>(y_t1 + (size_t)did * HD + kb + 16);
        s0.x += v0.x; s0.y += v0.y; s0.z += v0.z; s0.w += v0.w;
        s1.x += v1.x; s1.y += v1.y; s1.z += v1.z; s1.w += v1.w;
    }
    float dinv = 1.0f / fmaxf((float)deg, 1.0f);
    float4 x = *reinterpret_cast<const float4*>(xl + 4ull * (unsigned)node);

    float4 b0 = *reinterpret_cast<const float4*>(b1tl + kb);
    float4 b1 = *reinterpret_cast<const float4*>(b1tl + kb + 16);
    float4 wa0 = *reinterpret_cast<const float4*>(W1tl_r + 0 * HD + kb);
    float4 wa1 = *reinterpret_cast<const float4*>(W1tl_r + 1 * HD + kb);
    float4 wa2 = *reinterpret_cast<const float4*>(W1tl_r + 2 * HD + kb);
    float4 wa3 = *reinterpret_cast<const float4*>(W1tl_r + 3 * HD + kb);
    float4 wb0 = *reinterpret_cast<const float4*>(W1tl_r + 0 * HD + kb + 16);
    float4 wb1 = *reinterpret_cast<const float4*>(W1tl_r + 1 * HD + kb + 16);
    float4 wb2 = *reinterpret_cast<const float4*>(W1tl_r + 2 * HD + kb + 16);
    float4 wb3 = *reinterpret_cast<const float4*>(W1tl_r + 3 * HD + kb + 16);

    union { ushort us[8]; uint4 u; ushort4 h[2]; } o;
    o.us[0] = f2bf(fmaxf(s0.x * dinv + b0.x + x.x * wa0.x + x.y * wa1.x + x.z * wa2.x + x.w * wa3.x, 0.f));
    o.us[1] = f2bf(fmaxf(s0.y * dinv + b0.y + x.x * wa0.y + x.y * wa1.y + x.z * wa2.y + x.w * wa3.y, 0.f));
    o.us[2] = f2bf(fmaxf(s0.z * dinv + b0.z + x.x * wa0.z + x.y * wa1.z + x.z * wa2.z + x.w * wa3.z, 0.f));
    o.us[3] = f2bf(fmaxf(s0.w * dinv + b0.w + x.x * wa0.w + x.y * wa1.w + x.z * wa2.w + x.w * wa3.w, 0.f));
    o.us[4] = f2bf(fmaxf(s1.x * dinv + b1.x + x.x * wb0.x + x.y * wb1.x + x.z * wb2.x + x.w * wb3.x, 0.f));
    o.us[5] = f2bf(fmaxf(s1.y * dinv + b1.y + x.x * wb0.y + x.y * wb1.y + x.z * wb2.y + x.w * wb3.y, 0.f));
    o.us[6] = f2bf(fmaxf(s1.z * dinv + b1.z + x.x * wb0.z + x.y * wb1.z + x.z * wb2.z + x.w * wb3.z, 0.f));
    o.us[7] = f2bf(fmaxf(s1.w * dinv + b1.w + x.x * wb0.w + x.y * wb1.w + x.z * wb2.w + x.w * wb3.w, 0.f));

    *reinterpret_cast<ushort4*>(hlb + (size_t)node * HD + kb)      = o.h[0];
    *reinterpret_cast<ushort4*>(hlb + (size_t)node * HD + kb + 16) = o.h[1];
    int lane = (node & 15) + 16 * g;
    hlbf[(size_t)(blockIdx.x * 4 + ks) * 64 + lane] = o.u;
}

// ---------------------------------------------------------------------------
// K5+K6 merged: blockIdx < N_TGT -> target predictor (gather+GEMM);
//               else -> ligand MFMA predictor (4 tiles/block).
// ---------------------------------------------------------------------------
__global__ __launch_bounds__(256) void k_ptl(
    const ushort* __restrict__ hlb,
    const uint4* __restrict__ hlbf,
    const uint4* __restrict__ Wf,
    const float* __restrict__ y_t2,
    const int* __restrict__ bsrc, const int* __restrict__ cnt_src,
    const int* __restrict__ bdst, const int* __restrict__ cnt_dst,
    const float* __restrict__ Wlt,    // W2lt_l [128,128]
    const float* __restrict__ b2lt,
    const float* __restrict__ b2tl,
    const float* __restrict__ htW2r,
    const float* __restrict__ Wp,     // [256]
    float* __restrict__ p_t, float* __restrict__ p_l)
{
    __shared__ float sm[8][HD];
    __shared__ float msh[HD];
    __shared__ float sum2[2];

    if (blockIdx.x < N_TGT) {
        int row = blockIdx.x;
        int wg = threadIdx.x >> 5, c = threadIdx.x & 31;
        int deg = cnt_dst[row];
        int nn = min(deg, CAP_T);

        float4 s = make_float4(0.f, 0.f, 0.f, 0.f);
        for (int i = wg; i < nn; i += 8) {
            int sid = bdst[(size_t)row * CAP_T + i];
            ushort4 v = *reinterpret_cast<const ushort4*>(hlb + (size_t)sid * HD + c * 4);
            s.x += bf2f(v.x); s.y += bf2f(v.y); s.z += bf2f(v.z); s.w += bf2f(v.w);
        }
        *reinterpret_cast<float4*>(&sm[wg][c * 4]) = s;
        __syncthreads();

        if (threadIdx.x < HD) {
            int h = threadIdx.x;
            float dinv = 1.0f / fmaxf((float)deg, 1.0f);
            float acc = sm[0][h] + sm[1][h] + sm[2][h] + sm[3][h]
                      + sm[4][h] + sm[5][h] + sm[6][h] + sm[7][h];
            msh[h] = acc * dinv;
        }
        __syncthreads();

        if (threadIdx.x < HD) {
            int h = threadIdx.x;
            float g = 0.f;
            for (int k = 0; k < HD; k += 4) {
                float4 mk = *reinterpret_cast<const float4*>(&msh[k]);
                g += mk.x * Wlt[(size_t)(k + 0) * HD + h] + mk.y * Wlt[(size_t)(k + 1) * HD + h]
                   + mk.z * Wlt[(size_t)(k + 2) * HD + h] + mk.w * Wlt[(size_t)(k + 3) * HD + h];
            }
            float v = fmaxf(g + b2lt[h] + htW2r[(size_t)row * HD + h], 0.0f);
            float part = v * Wp[HD + h];
#pragma unroll
            for (int off = 1; off < 64; off <<= 1) part += __shfl_xor(part, off);
            if ((h & 63) == 0) sum2[h >> 6] = part;
        }
        __syncthreads();
        if (threadIdx.x == 0) p_t[row] = sum2[0] + sum2[1];
        return;
    }

    // ---- ligand branch ----
    int wid = threadIdx.x >> 6;
    int lane = threadIdx.x & 63;
    int l15 = lane & 15, g = lane >> 4;
    int tile = (blockIdx.x - N_TGT) * 4 + wid;
    int wrow0 = tile * 16;

    f32x4 acc[8];
#pragma unroll
    for (int ct = 0; ct < 8; ++ct) acc[ct] = (f32x4){0.f, 0.f, 0.f, 0.f};

#pragma unroll
    for (int ks = 0; ks < 4; ++ks) {
        union { uint4 u; short8v s; } ua;
        ua.u = hlbf[(size_t)(tile * 4 + ks) * 64 + lane];
#pragma unroll
        for (int ct = 0; ct < 8; ++ct) {
            union { uint4 u; short8v s; } ub;
            ub.u = Wf[(ks * 8 + ct) * 64 + lane];
            acc[ct] = __builtin_amdgcn_mfma_f32_16x16x32_bf16(ua.s, ub.s, acc[ct], 0, 0, 0);
        }
    }

    float wpv[8], bv[8];
#pragma unroll
    for (int ct = 0; ct < 8; ++ct) {
        int c = ct * 16 + l15;
        wpv[ct] = Wp[c];
        bv[ct]  = b2tl[c];
    }

#pragma unroll
    for (int j = 0; j < 4; ++j) {
        int row = wrow0 + g * 4 + j;
        bool valid = row < N_LIG;
        int deg = valid ? cnt_src[row] : 0;
        int nn = min(deg, CAP_L);
        float dinv = 1.0f / fmaxf((float)deg, 1.0f);
        float s[8];
#pragma unroll
        for (int ct = 0; ct < 8; ++ct) s[ct] = 0.f;
        for (int i = 0; i < nn; ++i) {
            int did = bsrc[(size_t)row * CAP_L + i];
            const float* yp = y_t2 + (size_t)did * HD + l15;
#pragma unroll
            for (int ct = 0; ct < 8; ++ct) s[ct] += yp[ct * 16];
        }
        float part = 0.f;
#pragma unroll
        for (int ct = 0; ct < 8; ++ct) {
            float v = acc[ct][j] + s[ct] * dinv + bv[ct];
            part += fmaxf(v, 0.f) * wpv[ct];
        }
#pragma unroll
        for (int off = 1; off < 16; off <<= 1) part += __shfl_xor(part, off);
        if (valid && l15 == 0) p_l[row] = part;
    }
}

// ---------------------------------------------------------------------------
// K7: out[e] = p_l[src[e]] + p_t[dst[e]] + bp
// ---------------------------------------------------------------------------
__global__ __launch_bounds__(256) void k_out(
    const int* __restrict__ src, const int* __restrict__ dst,
    const float* __restrict__ p_l, const float* __restrict__ p_t,
    const float* __restrict__ bp, float* __restrict__ out)
{
    int e = blockIdx.x * 256 + threadIdx.x;
    if (e >= NEDGE) return;
    out[e] = p_l[src[e]] + p_t[dst[e]] + bp[0];
}

// ---------------------------------------------------------------------------
extern "C" void kernel_launch(void* const* d_in, const int* in_sizes, int n_in,
                              void* d_out, int out_size, void* d_ws, size_t ws_size,
                              hipStream_t stream)
{
    const float* x_l    = (const float*)d_in[0];
    const float* x_t    = (const float*)d_in[1];
    const int*   ei     = (const int*)  d_in[2];
    const float* W1lt_l = (const float*)d_in[3];
    const float* b1lt   = (const float*)d_in[4];
    const float* W1lt_r = (const float*)d_in[5];
    const float* W1tl_l = (const float*)d_in[6];
    const float* b1tl   = (const float*)d_in[7];
    const float* W1tl_r = (const float*)d_in[8];
    const float* W2lt_l = (const float*)d_in[9];
    const float* b2lt   = (const float*)d_in[10];
    const float* W2lt_r = (const float*)d_in[11];
    const float* W2tl_l = (const float*)d_in[12];
    const float* b2tl   = (const float*)d_in[13];
    const float* W2tl_r = (const float*)d_in[14];
    const float* Wp     = (const float*)d_in[15];
    const float* bp     = (const float*)d_in[16];

    const int* src = ei;            // ligand indices
    const int* dst = ei + NEDGE;    // target indices

    char* ws = (char*)d_ws;
    size_t o = 0;
    int* cnt_src = (int*)(ws + o); o += (size_t)N_LIG * 4;
    int* cnt_dst = (int*)(ws + o); o += (size_t)N_TGT * 4;
    int* bsrc = (int*)(ws + o); o += (size_t)N_LIG * CAP_L * 4;
    int* bdst = (int*)(ws + o); o += (size_t)N_TGT * CAP_T * 4;
    ushort* hlb  = (ushort*)(ws + o); o += (size_t)N_LIG * HD * 2;
    uint4* hlbf  = (uint4*)(ws + o);  o += (size_t)NTILE_PAD * 4 * 64 * 16;
    uint4* Wf    = (uint4*)(ws + o);  o += (size_t)32 * 64 * 16;
    uint4* Wf1   = (uint4*)(ws + o);  o += (size_t)640 * 64 * 16;
    uint4* Wf2   = (uint4*)(ws + o);  o += (size_t)64 * 64 * 16;
    uint4* xtf   = (uint4*)(ws + o);  o += (size_t)10000 * 64 * 16;
    float* y_t1  = (float*)(ws + o); o += (size_t)N_TGT * HD * 4;
    float* y_t2  = (float*)(ws + o); o += (size_t)N_TGT * HD * 4;
    float* htW2r = (float*)(ws + o); o += (size_t)N_TGT * HD * 4;
    float* p_l   = (float*)(ws + o); o += (size_t)N_LIG * 4;
    float* p_t   = (float*)(ws + o); o += (size_t)N_TGT * 4;

    float* out = (float*)d_out;

    // merged prep: fragment packing (incl. conv2 weights) + counter zeroing
    k_pack<<<2786, 256, 0, stream>>>(W2tl_r, Wf, W1lt_r, W1tl_l, Wf1,
                                     x_t, xtf, (int4*)cnt_src,
                                     W2tl_l, W2lt_r, Wf2);

    k_fill<<<(NEDGE + 255) / 256, 256, 0, stream>>>(src, dst, cnt_src, cnt_dst, bsrc, bdst);

    // fused target pipeline: conv1 + neighbor-mean + conv2 projections
    k_tgt1m<<<N_TGT / 16, 256, 0, stream>>>(xtf, Wf1, Wf2, x_l, bdst, cnt_dst,
                                            W1lt_l, b1lt, y_t1, y_t2, htW2r);

    // ligand conv1 (dual layout)
    k_hl<<<NTILE_L, 256, 0, stream>>>(x_l, y_t1, bsrc, cnt_src, W1tl_r, b1tl, hlb, hlbf);

    // merged predictors (target gather-GEMM + ligand MFMA)
    k_ptl<<<N_TGT + PL_BLOCKS, 256, 0, stream>>>(hlb, hlbf, Wf, y_t2,
                                                 bsrc, cnt_src, bdst, cnt_dst,
                                                 W2lt_l, b2lt, b2tl, htW2r, Wp,
                                                 p_t, p_l);

    // edges
    k_out<<<(NEDGE + 255) / 256, 256, 0, stream>>>(src, dst, p_l, p_t, bp, out);
}

// Round 10
// 117.951 us; speedup vs baseline: 1.3967x; 1.1581x over previous
//
#include <hip/hip_runtime.h>
#include <hip/hip_bf16.h>

#define N_LIG 100000
#define N_TGT 4000
#define NEDGE 150000
#define DT 1280
#define HD 128
#define CAP_L 32
#define CAP_T 128
#define NTILE_L 6250            // N_LIG / 16
#define NTILE_PAD 6252
#define PL_BLOCKS 1563          // ceil(NTILE_L/4)

typedef __attribute__((ext_vector_type(8))) short short8v;
typedef __attribute__((ext_vector_type(4))) float f32x4;

static __device__ __forceinline__ ushort f2bf(float f) {
    __hip_bfloat16 h = __float2bfloat16(f);
    union { __hip_bfloat16 h; ushort u; } c; c.h = h; return c.u;
}
static __device__ __forceinline__ float bf2f(ushort u) {
    union { unsigned v; float f; } c; c.v = ((unsigned)u) << 16; return c.f;
}

// ---------------------------------------------------------------------------
// K0: merged prep — fragment packing for all MFMA operands + counter zeroing.
// ---------------------------------------------------------------------------
__global__ __launch_bounds__(256) void k_pack(
    const float* __restrict__ W2, uint4* __restrict__ Wf,
    const float* __restrict__ Wr, const float* __restrict__ Wl,
    uint4* __restrict__ Wf1,
    const float* __restrict__ xt, uint4* __restrict__ xtf,
    int4* __restrict__ cntz,
    const float* __restrict__ W2a, const float* __restrict__ W2b,
    uint4* __restrict__ Wf2)
{
    int bx = blockIdx.x;
    if (bx < 8) {
        int gid = bx * 256 + threadIdx.x;           // 2048
        int lane = gid & 63, frag = gid >> 6;       // frag 0..31
        int ks = frag >> 3, ct = frag & 7;
        int l15 = lane & 15, g = lane >> 4;
        int k = ks * 32 + g * 4, n = ct * 16 + l15;
        union { ushort us[8]; uint4 u; } o;
#pragma unroll
        for (int j = 0; j < 4; ++j) {
            o.us[j]     = f2bf(W2[(size_t)(k + j) * HD + n]);
            o.us[4 + j] = f2bf(W2[(size_t)(k + 16 + j) * HD + n]);
        }
        Wf[gid] = o.u;
    } else if (bx < 168) {
        int gid = (bx - 8) * 256 + threadIdx.x;     // 40960
        int lane = gid & 63, frag = gid >> 6;       // 0..639
        int ks = frag >> 4, nct = frag & 15;
        int l15 = lane & 15, g = lane >> 4;
        int k = ks * 32 + g * 4, n = nct * 16 + l15;
        const float* Ws = (n < HD) ? Wr : Wl;
        int nn = n & 127;
        union { ushort us[8]; uint4 u; } o;
#pragma unroll
        for (int j = 0; j < 4; ++j) {
            o.us[j]     = f2bf(Ws[(size_t)(k + j) * HD + nn]);
            o.us[4 + j] = f2bf(Ws[(size_t)(k + 16 + j) * HD + nn]);
        }
        Wf1[gid] = o.u;
    } else if (bx < 2668) {
        int gid = (bx - 168) * 256 + threadIdx.x;   // 640000
        int lane = gid & 63, frag = gid >> 6;       // 0..9999
        int ks = frag % 40, rt = frag / 40;
        int row = rt * 16 + (lane & 15);
        int kb = ks * 32 + (lane >> 4) * 4;
        float4 a0 = *reinterpret_cast<const float4*>(xt + (size_t)row * DT + kb);
        float4 a1 = *reinterpret_cast<const float4*>(xt + (size_t)row * DT + kb + 16);
        union { ushort us[8]; uint4 u; } o;
        o.us[0] = f2bf(a0.x); o.us[1] = f2bf(a0.y); o.us[2] = f2bf(a0.z); o.us[3] = f2bf(a0.w);
        o.us[4] = f2bf(a1.x); o.us[5] = f2bf(a1.y); o.us[6] = f2bf(a1.z); o.us[7] = f2bf(a1.w);
        xtf[gid] = o.u;
    } else if (bx < 2770) {
        int i = (bx - 2668) * 256 + threadIdx.x;
        if (i < 26000) cntz[i] = make_int4(0, 0, 0, 0);
    } else {
        int gid = (bx - 2770) * 256 + threadIdx.x;  // 4096
        int lane = gid & 63, frag = gid >> 6;       // 0..63
        int ks = frag >> 4, nct = frag & 15;
        int l15 = lane & 15, g = lane >> 4;
        int k = ks * 32 + g * 4, n = nct * 16 + l15;
        const float* Ws = (n < HD) ? W2a : W2b;
        int nn = n & 127;
        union { ushort us[8]; uint4 u; } o;
#pragma unroll
        for (int j = 0; j < 4; ++j) {
            o.us[j]     = f2bf(Ws[(size_t)(k + j) * HD + nn]);
            o.us[4 + j] = f2bf(Ws[(size_t)(k + 16 + j) * HD + nn]);
        }
        Wf2[gid] = o.u;
    }
}

// ---------------------------------------------------------------------------
// K1: build adjacency buckets (int atomics only).
// ---------------------------------------------------------------------------
__global__ __launch_bounds__(256) void k_fill(
    const int* __restrict__ src, const int* __restrict__ dst,
    int* __restrict__ cnt_src, int* __restrict__ cnt_dst,
    int* __restrict__ bsrc, int* __restrict__ bdst)
{
    int e = blockIdx.x * 256 + threadIdx.x;
    if (e >= NEDGE) return;
    int s = src[e], d = dst[e];
    int ps = atomicAdd(&cnt_src[s], 1);
    if (ps < CAP_L) bsrc[(size_t)s * CAP_L + ps] = d;
    int pd = atomicAdd(&cnt_dst[d], 1);
    if (pd < CAP_T) bdst[(size_t)d * CAP_T + pd] = s;
}

// ---------------------------------------------------------------------------
// K2: fused target pipeline, 512 threads (8 waves) for 2x TLP.
//   phase A: m_t = mean(x_l[nbr]) into LDS (threads 0..127)
//   phase B: D = x_t @ {W1lt_r|W1tl_l} MFMA, each wave 2 col-tiles
//   phase C: h_t -> LDS bf16 (waves 0-3); y_t1 -> global (waves 4-7)
//   phase D: {y_t2|htW2r} = h_t @ {W2tl_l|W2lt_r} MFMA from LDS
// ---------------------------------------------------------------------------
__global__ __launch_bounds__(512) void k_tgt1m(
    const uint4* __restrict__ xtf,    // [250*40][64] bf16 A-frags
    const uint4* __restrict__ Wf1,    // [640][64] bf16 B-frags
    const uint4* __restrict__ Wf2,    // [64][64] bf16 B-frags (conv2)
    const float* __restrict__ xl,
    const int* __restrict__ bdst, const int* __restrict__ cnt_dst,
    const float* __restrict__ W1lt_l, // [4,128]
    const float* __restrict__ b1lt,
    float* __restrict__ y_t1,
    float* __restrict__ y_t2, float* __restrict__ htW2r)
{
    __shared__ float  ms[16][4];
    __shared__ ushort hts[16][136];   // padded row stride

    int w = threadIdx.x >> 6;         // 0..7
    int lane = threadIdx.x & 63;
    int l15 = lane & 15, g = lane >> 4;
    int rt = blockIdx.x;
    int row0 = rt * 16;

    // phase A
    if (threadIdx.x < 128) {
        int r = threadIdx.x >> 3, lane8 = threadIdx.x & 7;
        int row = row0 + r;
        int deg = cnt_dst[row];
        int n = min(deg, CAP_T);
        float4 acc = make_float4(0.f, 0.f, 0.f, 0.f);
        for (int i = lane8; i < n; i += 8) {
            int sid = bdst[(size_t)row * CAP_T + i];
            float4 x = *reinterpret_cast<const float4*>(xl + 4ull * (unsigned)sid);
            acc.x += x.x; acc.y += x.y; acc.z += x.z; acc.w += x.w;
        }
#pragma unroll
        for (int off = 1; off < 8; off <<= 1) {
            acc.x += __shfl_xor(acc.x, off); acc.y += __shfl_xor(acc.y, off);
            acc.z += __shfl_xor(acc.z, off); acc.w += __shfl_xor(acc.w, off);
        }
        if (lane8 == 0) {
            float dinv = 1.0f / fmaxf((float)deg, 1.0f);
            ms[r][0] = acc.x * dinv; ms[r][1] = acc.y * dinv;
            ms[r][2] = acc.z * dinv; ms[r][3] = acc.w * dinv;
        }
    }

    // phase B
    f32x4 acc[2];
#pragma unroll
    for (int ct = 0; ct < 2; ++ct) acc[ct] = (f32x4){0.f, 0.f, 0.f, 0.f};

    for (int ks = 0; ks < DT / 32; ++ks) {
        union { uint4 u; short8v s; } ua;
        ua.u = xtf[(size_t)(rt * 40 + ks) * 64 + lane];
#pragma unroll
        for (int ct = 0; ct < 2; ++ct) {
            union { uint4 u; short8v s; } ub;
            ub.u = Wf1[(size_t)(ks * 16 + w * 2 + ct) * 64 + lane];
            acc[ct] = __builtin_amdgcn_mfma_f32_16x16x32_bf16(ua.s, ub.s, acc[ct], 0, 0, 0);
        }
    }

    __syncthreads();

    // phase C
    if (w < 4) {
#pragma unroll
        for (int ct = 0; ct < 2; ++ct) {
            int c = w * 32 + ct * 16 + l15;
            float wl0 = W1lt_l[c], wl1 = W1lt_l[HD + c],
                  wl2 = W1lt_l[2 * HD + c], wl3 = W1lt_l[3 * HD + c];
            float bb = b1lt[c];
#pragma unroll
            for (int j = 0; j < 4; ++j) {
                int r = 4 * g + j;
                float v = acc[ct][j] + bb + ms[r][0] * wl0 + ms[r][1] * wl1
                        + ms[r][2] * wl2 + ms[r][3] * wl3;
                hts[r][c] = f2bf(fmaxf(v, 0.0f));
            }
        }
    } else {
#pragma unroll
        for (int ct = 0; ct < 2; ++ct) {
            int c = (w - 4) * 32 + ct * 16 + l15;
#pragma unroll
            for (int j = 0; j < 4; ++j) {
                int grow = row0 + 4 * g + j;
                y_t1[(size_t)grow * HD + c] = acc[ct][j];
            }
        }
    }
    __syncthreads();

    // phase D
    f32x4 acc2[2];
#pragma unroll
    for (int ct = 0; ct < 2; ++ct) acc2[ct] = (f32x4){0.f, 0.f, 0.f, 0.f};

#pragma unroll
    for (int ks2 = 0; ks2 < 4; ++ks2) {
        int kb2 = ks2 * 32 + g * 4;
        union { ushort us[8]; short8v s; } ua2;
        *reinterpret_cast<ushort4*>(&ua2.us[0]) =
            *reinterpret_cast<const ushort4*>(&hts[l15][kb2]);
        *reinterpret_cast<ushort4*>(&ua2.us[4]) =
            *reinterpret_cast<const ushort4*>(&hts[l15][kb2 + 16]);
#pragma unroll
        for (int ct = 0; ct < 2; ++ct) {
            union { uint4 u; short8v s; } ub2;
            ub2.u = Wf2[(size_t)(ks2 * 16 + w * 2 + ct) * 64 + lane];
            acc2[ct] = __builtin_amdgcn_mfma_f32_16x16x32_bf16(ua2.s, ub2.s, acc2[ct], 0, 0, 0);
        }
    }

    float* outp = (w < 4) ? y_t2 : htW2r;
    int cw = (w < 4) ? w : (w - 4);
#pragma unroll
    for (int ct = 0; ct < 2; ++ct) {
        int c = cw * 32 + ct * 16 + l15;
#pragma unroll
        for (int j = 0; j < 4; ++j) {
            int grow = row0 + 4 * g + j;
            outp[(size_t)grow * HD + c] = acc2[ct][j];
        }
    }
}

// ---------------------------------------------------------------------------
// K3: fused ligand conv1 -> hlb (row layout) + hlbf (fragment layout).
// ---------------------------------------------------------------------------
__global__ __launch_bounds__(256) void k_hl(
    const float* __restrict__ xl, const float* __restrict__ y_t1,
    const int* __restrict__ bsrc, const int* __restrict__ cnt_src,
    const float* __restrict__ W1tl_r,  // [4,128]
    const float* __restrict__ b1tl,
    ushort* __restrict__ hlb, uint4* __restrict__ hlbf)
{
    int tc = threadIdx.x & 15;
    int node = blockIdx.x * 16 + (threadIdx.x >> 4);
    int ks = tc >> 2, g = tc & 3;
    int kb = ks * 32 + g * 4;

    int deg = cnt_src[node];
    int n = min(deg, CAP_L);
    float4 s0 = make_float4(0.f, 0.f, 0.f, 0.f);
    float4 s1 = make_float4(0.f, 0.f, 0.f, 0.f);
    for (int i = 0; i < n; ++i) {
        int did = bsrc[(size_t)node * CAP_L + i];
        float4 v0 = *reinterpret_cast<const float4*>(y_t1 + (size_t)did * HD + kb);
        float4 v1 = *reinterpret_cast<const float4*>(y_t1 + (size_t)did * HD + kb + 16);
        s0.x += v0.x; s0.y += v0.y; s0.z += v0.z; s0.w += v0.w;
        s1.x += v1.x; s1.y += v1.y; s1.z += v1.z; s1.w += v1.w;
    }
    float dinv = 1.0f / fmaxf((float)deg, 1.0f);
    float4 x = *reinterpret_cast<const float4*>(xl + 4ull * (unsigned)node);

    float4 b0 = *reinterpret_cast<const float4*>(b1tl + kb);
    float4 b1 = *reinterpret_cast<const float4*>(b1tl + kb + 16);
    float4 wa0 = *reinterpret_cast<const float4*>(W1tl_r + 0 * HD + kb);
    float4 wa1 = *reinterpret_cast<const float4*>(W1tl_r + 1 * HD + kb);
    float4 wa2 = *reinterpret_cast<const float4*>(W1tl_r + 2 * HD + kb);
    float4 wa3 = *reinterpret_cast<const float4*>(W1tl_r + 3 * HD + kb);
    float4 wb0 = *reinterpret_cast<const float4*>(W1tl_r + 0 * HD + kb + 16);
    float4 wb1 = *reinterpret_cast<const float4*>(W1tl_r + 1 * HD + kb + 16);
    float4 wb2 = *reinterpret_cast<const float4*>(W1tl_r + 2 * HD + kb + 16);
    float4 wb3 = *reinterpret_cast<const float4*>(W1tl_r + 3 * HD + kb + 16);

    union { ushort us[8]; uint4 u; ushort4 h[2]; } o;
    o.us[0] = f2bf(fmaxf(s0.x * dinv + b0.x + x.x * wa0.x + x.y * wa1.x + x.z * wa2.x + x.w * wa3.x, 0.f));
    o.us[1] = f2bf(fmaxf(s0.y * dinv + b0.y + x.x * wa0.y + x.y * wa1.y + x.z * wa2.y + x.w * wa3.y, 0.f));
    o.us[2] = f2bf(fmaxf(s0.z * dinv + b0.z + x.x * wa0.z + x.y * wa1.z + x.z * wa2.z + x.w * wa3.z, 0.f));
    o.us[3] = f2bf(fmaxf(s0.w * dinv + b0.w + x.x * wa0.w + x.y * wa1.w + x.z * wa2.w + x.w * wa3.w, 0.f));
    o.us[4] = f2bf(fmaxf(s1.x * dinv + b1.x + x.x * wb0.x + x.y * wb1.x + x.z * wb2.x + x.w * wb3.x, 0.f));
    o.us[5] = f2bf(fmaxf(s1.y * dinv + b1.y + x.x * wb0.y + x.y * wb1.y + x.z * wb2.y + x.w * wb3.y, 0.f));
    o.us[6] = f2bf(fmaxf(s1.z * dinv + b1.z + x.x * wb0.z + x.y * wb1.z + x.z * wb2.z + x.w * wb3.z, 0.f));
    o.us[7] = f2bf(fmaxf(s1.w * dinv + b1.w + x.x * wb0.w + x.y * wb1.w + x.z * wb2.w + x.w * wb3.w, 0.f));

    *reinterpret_cast<ushort4*>(hlb + (size_t)node * HD + kb)      = o.h[0];
    *reinterpret_cast<ushort4*>(hlb + (size_t)node * HD + kb + 16) = o.h[1];
    int lane = (node & 15) + 16 * g;
    hlbf[(size_t)(blockIdx.x * 4 + ks) * 64 + lane] = o.u;
}

// ---------------------------------------------------------------------------
// K5+K6 merged predictors.
//   blockIdx < N_TGT: target row — LDS-staged indices + 16x16 ushort8 gather
//   else: ligand MFMA predictor (4 tiles/block)
// ---------------------------------------------------------------------------
__global__ __launch_bounds__(256) void k_ptl(
    const ushort* __restrict__ hlb,
    const uint4* __restrict__ hlbf,
    const uint4* __restrict__ Wf,
    const float* __restrict__ y_t2,
    const int* __restrict__ bsrc, const int* __restrict__ cnt_src,
    const int* __restrict__ bdst, const int* __restrict__ cnt_dst,
    const float* __restrict__ Wlt,    // W2lt_l [128,128]
    const float* __restrict__ b2lt,
    const float* __restrict__ b2tl,
    const float* __restrict__ htW2r,
    const float* __restrict__ Wp,     // [256]
    float* __restrict__ p_t, float* __restrict__ p_l)
{
    __shared__ int   idx[CAP_T];
    __shared__ float sm[16][132];
    __shared__ float msh[HD];
    __shared__ float sum2[2];

    if (blockIdx.x < N_TGT) {
        int row = blockIdx.x;
        int deg = cnt_dst[row];
        int nn = min(deg, CAP_T);

        // stage neighbor indices (coalesced, removes one dependency level)
        if (threadIdx.x < CAP_T) idx[threadIdx.x] = bdst[(size_t)row * CAP_T + threadIdx.x];
        __syncthreads();

        // 16 groups x 16 lanes; lane loads 16B (8 bf16) -> serial depth ~2.3
        int wg = threadIdx.x >> 4, l16 = threadIdx.x & 15;
        float s[8];
#pragma unroll
        for (int j = 0; j < 8; ++j) s[j] = 0.f;
        for (int i = wg; i < nn; i += 16) {
            int sid = idx[i];
            union { uint4 u; ushort us[8]; } v;
            v.u = *reinterpret_cast<const uint4*>(hlb + (size_t)sid * HD + l16 * 8);
#pragma unroll
            for (int j = 0; j < 8; ++j) s[j] += bf2f(v.us[j]);
        }
#pragma unroll
        for (int j = 0; j < 8; ++j) sm[wg][l16 * 8 + j] = s[j];
        __syncthreads();

        if (threadIdx.x < HD) {
            int h = threadIdx.x;
            float dinv = 1.0f / fmaxf((float)deg, 1.0f);
            float acc = 0.f;
#pragma unroll
            for (int w2 = 0; w2 < 16; ++w2) acc += sm[w2][h];
            msh[h] = acc * dinv;
        }
        __syncthreads();

        if (threadIdx.x < HD) {
            int h = threadIdx.x;
            float g = 0.f;
            for (int k = 0; k < HD; k += 4) {
                float4 mk = *reinterpret_cast<const float4*>(&msh[k]);
                g += mk.x * Wlt[(size_t)(k + 0) * HD + h] + mk.y * Wlt[(size_t)(k + 1) * HD + h]
                   + mk.z * Wlt[(size_t)(k + 2) * HD + h] + mk.w * Wlt[(size_t)(k + 3) * HD + h];
            }
            float v = fmaxf(g + b2lt[h] + htW2r[(size_t)row * HD + h], 0.0f);
            float part = v * Wp[HD + h];
#pragma unroll
            for (int off = 1; off < 64; off <<= 1) part += __shfl_xor(part, off);
            if ((h & 63) == 0) sum2[h >> 6] = part;
        }
        __syncthreads();
        if (threadIdx.x == 0) p_t[row] = sum2[0] + sum2[1];
        return;
    }

    // ---- ligand branch ----
    int wid = threadIdx.x >> 6;
    int lane = threadIdx.x & 63;
    int l15 = lane & 15, g = lane >> 4;
    int tile = (blockIdx.x - N_TGT) * 4 + wid;
    int wrow0 = tile * 16;

    f32x4 acc[8];
#pragma unroll
    for (int ct = 0; ct < 8; ++ct) acc[ct] = (f32x4){0.f, 0.f, 0.f, 0.f};

#pragma unroll
    for (int ks = 0; ks < 4; ++ks) {
        union { uint4 u; short8v s; } ua;
        ua.u = hlbf[(size_t)(tile * 4 + ks) * 64 + lane];
#pragma unroll
        for (int ct = 0; ct < 8; ++ct) {
            union { uint4 u; short8v s; } ub;
            ub.u = Wf[(ks * 8 + ct) * 64 + lane];
            acc[ct] = __builtin_amdgcn_mfma_f32_16x16x32_bf16(ua.s, ub.s, acc[ct], 0, 0, 0);
        }
    }

    float wpv[8], bv[8];
#pragma unroll
    for (int ct = 0; ct < 8; ++ct) {
        int c = ct * 16 + l15;
        wpv[ct] = Wp[c];
        bv[ct]  = b2tl[c];
    }

#pragma unroll
    for (int j = 0; j < 4; ++j) {
        int row = wrow0 + g * 4 + j;
        bool valid = row < N_LIG;
        int deg = valid ? cnt_src[row] : 0;
        int nn = min(deg, CAP_L);
        float dinv = 1.0f / fmaxf((float)deg, 1.0f);
        float s[8];
#pragma unroll
        for (int ct = 0; ct < 8; ++ct) s[ct] = 0.f;
        for (int i = 0; i < nn; ++i) {
            int did = bsrc[(size_t)row * CAP_L + i];
            const float* yp = y_t2 + (size_t)did * HD + l15;
#pragma unroll
            for (int ct = 0; ct < 8; ++ct) s[ct] += yp[ct * 16];
        }
        float part = 0.f;
#pragma unroll
        for (int ct = 0; ct < 8; ++ct) {
            float v = acc[ct][j] + s[ct] * dinv + bv[ct];
            part += fmaxf(v, 0.f) * wpv[ct];
        }
#pragma unroll
        for (int off = 1; off < 16; off <<= 1) part += __shfl_xor(part, off);
        if (valid && l15 == 0) p_l[row] = part;
    }
}

// ---------------------------------------------------------------------------
// K7: out[e] = p_l[src[e]] + p_t[dst[e]] + bp
// ---------------------------------------------------------------------------
__global__ __launch_bounds__(256) void k_out(
    const int* __restrict__ src, const int* __restrict__ dst,
    const float* __restrict__ p_l, const float* __restrict__ p_t,
    const float* __restrict__ bp, float* __restrict__ out)
{
    int e = blockIdx.x * 256 + threadIdx.x;
    if (e >= NEDGE) return;
    out[e] = p_l[src[e]] + p_t[dst[e]] + bp[0];
}

// ---------------------------------------------------------------------------
extern "C" void kernel_launch(void* const* d_in, const int* in_sizes, int n_in,
                              void* d_out, int out_size, void* d_ws, size_t ws_size,
                              hipStream_t stream)
{
    const float* x_l    = (const float*)d_in[0];
    const float* x_t    = (const float*)d_in[1];
    const int*   ei     = (const int*)  d_in[2];
    const float* W1lt_l = (const float*)d_in[3];
    const float* b1lt   = (const float*)d_in[4];
    const float* W1lt_r = (const float*)d_in[5];
    const float* W1tl_l = (const float*)d_in[6];
    const float* b1tl   = (const float*)d_in[7];
    const float* W1tl_r = (const float*)d_in[8];
    const float* W2lt_l = (const float*)d_in[9];
    const float* b2lt   = (const float*)d_in[10];
    const float* W2lt_r = (const float*)d_in[11];
    const float* W2tl_l = (const float*)d_in[12];
    const float* b2tl   = (const float*)d_in[13];
    const float* W2tl_r = (const float*)d_in[14];
    const float* Wp     = (const float*)d_in[15];
    const float* bp     = (const float*)d_in[16];

    const int* src = ei;            // ligand indices
    const int* dst = ei + NEDGE;    // target indices

    char* ws = (char*)d_ws;
    size_t o = 0;
    int* cnt_src = (int*)(ws + o); o += (size_t)N_LIG * 4;
    int* cnt_dst = (int*)(ws + o); o += (size_t)N_TGT * 4;
    int* bsrc = (int*)(ws + o); o += (size_t)N_LIG * CAP_L * 4;
    int* bdst = (int*)(ws + o); o += (size_t)N_TGT * CAP_T * 4;
    ushort* hlb  = (ushort*)(ws + o); o += (size_t)N_LIG * HD * 2;
    uint4* hlbf  = (uint4*)(ws + o);  o += (size_t)NTILE_PAD * 4 * 64 * 16;
    uint4* Wf    = (uint4*)(ws + o);  o += (size_t)32 * 64 * 16;
    uint4* Wf1   = (uint4*)(ws + o);  o += (size_t)640 * 64 * 16;
    uint4* Wf2   = (uint4*)(ws + o);  o += (size_t)64 * 64 * 16;
    uint4* xtf   = (uint4*)(ws + o);  o += (size_t)10000 * 64 * 16;
    float* y_t1  = (float*)(ws + o); o += (size_t)N_TGT * HD * 4;
    float* y_t2  = (float*)(ws + o); o += (size_t)N_TGT * HD * 4;
    float* htW2r = (float*)(ws + o); o += (size_t)N_TGT * HD * 4;
    float* p_l   = (float*)(ws + o); o += (size_t)N_LIG * 4;
    float* p_t   = (float*)(ws + o); o += (size_t)N_TGT * 4;

    float* out = (float*)d_out;

    // merged prep: fragment packing (incl. conv2 weights) + counter zeroing
    k_pack<<<2786, 256, 0, stream>>>(W2tl_r, Wf, W1lt_r, W1tl_l, Wf1,
                                     x_t, xtf, (int4*)cnt_src,
                                     W2tl_l, W2lt_r, Wf2);

    k_fill<<<(NEDGE + 255) / 256, 256, 0, stream>>>(src, dst, cnt_src, cnt_dst, bsrc, bdst);

    // fused target pipeline: conv1 + neighbor-mean + conv2 projections
    k_tgt1m<<<N_TGT / 16, 512, 0, stream>>>(xtf, Wf1, Wf2, x_l, bdst, cnt_dst,
                                            W1lt_l, b1lt, y_t1, y_t2, htW2r);

    // ligand conv1 (dual layout)
    k_hl<<<NTILE_L, 256, 0, stream>>>(x_l, y_t1, bsrc, cnt_src, W1tl_r, b1tl, hlb, hlbf);

    // merged predictors (target gather-GEMM + ligand MFMA)
    k_ptl<<<N_TGT + PL_BLOCKS, 256, 0, stream>>>(hlb, hlbf, Wf, y_t2,
                                                 bsrc, cnt_src, bdst, cnt_dst,
                                                 W2lt_l, b2lt, b2tl, htW2r, Wp,
                                                 p_t, p_l);

    // edges
    k_out<<<(NEDGE + 255) / 256, 256, 0, stream>>>(src, dst, p_l, p_t, bp, out);
}